// Round 1
// baseline (1513.684 us; speedup 1.0000x reference)
//
#include <hip/hip_runtime.h>
#include <math.h>

#define NN 50000
#define FIN 128
#define HH 4
#define CC 64
#define HC (HH*CC)       // 256
#define GG 512
#define EE 800000
#define ET (EE + NN)     // 850000 edges incl. self-loops
#define NEG_SLOPE 0.2f

__device__ __forceinline__ void atomicMaxFloat(float* addr, float val) {
    if (val >= 0.f) atomicMax((int*)addr, __float_as_int(val));
    else            atomicMin((unsigned int*)addr, __float_as_uint(val));
}

__device__ __forceinline__ float waveReduceSum(float v) {
    #pragma unroll
    for (int off = 32; off > 0; off >>= 1) v += __shfl_xor(v, off);
    return v;
}

// Fill amax regions with -inf, accumulator regions with 0.
__global__ __launch_bounds__(256) void init_kernel(float* __restrict__ amaxr,
                                                   float* __restrict__ zeror) {
    const size_t amax_n = (size_t)NN * (HH + 1);                       // amax1 + amax2
    const size_t zero_n = (size_t)NN * (HH + 1)                       // denom1 + denom2
                        + (size_t)NN * HC + (size_t)NN * CC            // out1 + out2
                        + (size_t)GG * CC + GG;                        // pooled + cnt
    size_t stride = (size_t)gridDim.x * 256;
    for (size_t j = (size_t)blockIdx.x * 256 + threadIdx.x; j < amax_n; j += stride)
        amaxr[j] = -INFINITY;
    for (size_t j = (size_t)blockIdx.x * 256 + threadIdx.x; j < zero_n; j += stride)
        zeror[j] = 0.f;
}

// h1 = x @ W1  [N,256]; fused a_s1/a_d1 [N,4]. 8 nodes per 256-thread block.
__global__ __launch_bounds__(256) void gemm1_kernel(
    const float* __restrict__ x, const float* __restrict__ W1,
    const float* __restrict__ att_src1, const float* __restrict__ att_dst1,
    float* __restrict__ h1, float* __restrict__ a_s1, float* __restrict__ a_d1)
{
    __shared__ float xs[8][FIN];
    int n0 = blockIdx.x * 8;
    int t = threadIdx.x;
    for (int i = t; i < 8 * FIN; i += 256) {
        int r = i >> 7, k = i & 127;
        xs[r][k] = x[(size_t)(n0 + r) * FIN + k];   // grid exact: 50000 = 6250*8
    }
    __syncthreads();
    float acc[8];
    #pragma unroll
    for (int r = 0; r < 8; ++r) acc[r] = 0.f;
    for (int k = 0; k < FIN; ++k) {
        float w = W1[k * HC + t];
        #pragma unroll
        for (int r = 0; r < 8; ++r) acc[r] += xs[r][k] * w;
    }
    int head = t >> 6, lane = t & 63;
    float asw = att_src1[head * CC + lane];
    float adw = att_dst1[head * CC + lane];
    #pragma unroll
    for (int r = 0; r < 8; ++r) {
        int n = n0 + r;
        h1[(size_t)n * HC + t] = acc[r];
        float vs = waveReduceSum(acc[r] * asw);
        float vd = waveReduceSum(acc[r] * adw);
        if (lane == 0) { a_s1[n * HH + head] = vs; a_d1[n * HH + head] = vd; }
    }
}

__global__ __launch_bounds__(256) void emax1_kernel(const int* __restrict__ ei,
    const float* __restrict__ a_s, const float* __restrict__ a_d, float* __restrict__ amax)
{
    int e = blockIdx.x * 256 + threadIdx.x;
    if (e >= ET) return;
    int s, d;
    if (e < EE) { s = ei[e]; d = ei[EE + e]; } else { s = d = e - EE; }
    #pragma unroll
    for (int h = 0; h < HH; ++h) {
        float a = a_s[s * HH + h] + a_d[d * HH + h];
        a = (a > 0.f) ? a : NEG_SLOPE * a;
        atomicMaxFloat(&amax[d * HH + h], a);
    }
}

__global__ __launch_bounds__(256) void esum1_kernel(const int* __restrict__ ei,
    const float* __restrict__ a_s, const float* __restrict__ a_d,
    const float* __restrict__ amax, float* __restrict__ denom)
{
    int e = blockIdx.x * 256 + threadIdx.x;
    if (e >= ET) return;
    int s, d;
    if (e < EE) { s = ei[e]; d = ei[EE + e]; } else { s = d = e - EE; }
    #pragma unroll
    for (int h = 0; h < HH; ++h) {
        float a = a_s[s * HH + h] + a_d[d * HH + h];
        a = (a > 0.f) ? a : NEG_SLOPE * a;
        atomicAdd(&denom[d * HH + h], expf(a - amax[d * HH + h]));
    }
}

// one 64-lane wave per edge; 4 heads x 64 channels scatter
__global__ __launch_bounds__(256) void emsg1_kernel(const int* __restrict__ ei,
    const float* __restrict__ a_s, const float* __restrict__ a_d,
    const float* __restrict__ amax, const float* __restrict__ denom,
    const float* __restrict__ h1, float* __restrict__ out1)
{
    int wid = blockIdx.x * 4 + (threadIdx.x >> 6);
    if (wid >= ET) return;
    int lane = threadIdx.x & 63;
    int s, d;
    if (wid < EE) { s = ei[wid]; d = ei[EE + wid]; } else { s = d = wid - EE; }
    #pragma unroll
    for (int h = 0; h < HH; ++h) {
        float a = a_s[s * HH + h] + a_d[d * HH + h];
        a = (a > 0.f) ? a : NEG_SLOPE * a;
        float w = expf(a - amax[d * HH + h]) / (denom[d * HH + h] + 1e-16f);
        float v = h1[(size_t)s * HC + h * CC + lane] * w;
        atomicAdd(&out1[(size_t)d * HC + h * CC + lane], v);
    }
}

// h2 = relu(out1 + b1) @ W2  [N,64]; fused a_s2/a_d2. 32 nodes per block (4 waves x 8).
__global__ __launch_bounds__(256) void gemm2_kernel(
    const float* __restrict__ out1, const float* __restrict__ b1,
    const float* __restrict__ W2, const float* __restrict__ att_src2,
    const float* __restrict__ att_dst2,
    float* __restrict__ h2, float* __restrict__ a_s2, float* __restrict__ a_d2)
{
    __shared__ float xs[32][HC];
    int n0 = blockIdx.x * 32;
    int t = threadIdx.x;
    float bb = b1[t];
    for (int r = 0; r < 32; ++r) {
        int n = n0 + r;
        float v = (n < NN) ? out1[(size_t)n * HC + t] + bb : 0.f;
        xs[r][t] = v > 0.f ? v : 0.f;
    }
    __syncthreads();
    int wv = t >> 6, lane = t & 63;
    float acc[8];
    #pragma unroll
    for (int r = 0; r < 8; ++r) acc[r] = 0.f;
    for (int k = 0; k < HC; ++k) {
        float w = W2[k * CC + lane];
        #pragma unroll
        for (int r = 0; r < 8; ++r) acc[r] += xs[wv * 8 + r][k] * w;
    }
    float asw = att_src2[lane], adw = att_dst2[lane];
    #pragma unroll
    for (int r = 0; r < 8; ++r) {
        int n = n0 + wv * 8 + r;
        float vs = waveReduceSum(acc[r] * asw);
        float vd = waveReduceSum(acc[r] * adw);
        if (n < NN) {
            h2[(size_t)n * CC + lane] = acc[r];
            if (lane == 0) { a_s2[n] = vs; a_d2[n] = vd; }
        }
    }
}

__global__ __launch_bounds__(256) void emax2_kernel(const int* __restrict__ ei,
    const float* __restrict__ a_s, const float* __restrict__ a_d, float* __restrict__ amax)
{
    int e = blockIdx.x * 256 + threadIdx.x;
    if (e >= ET) return;
    int s, d;
    if (e < EE) { s = ei[e]; d = ei[EE + e]; } else { s = d = e - EE; }
    float a = a_s[s] + a_d[d];
    a = (a > 0.f) ? a : NEG_SLOPE * a;
    atomicMaxFloat(&amax[d], a);
}

__global__ __launch_bounds__(256) void esum2_kernel(const int* __restrict__ ei,
    const float* __restrict__ a_s, const float* __restrict__ a_d,
    const float* __restrict__ amax, float* __restrict__ denom)
{
    int e = blockIdx.x * 256 + threadIdx.x;
    if (e >= ET) return;
    int s, d;
    if (e < EE) { s = ei[e]; d = ei[EE + e]; } else { s = d = e - EE; }
    float a = a_s[s] + a_d[d];
    a = (a > 0.f) ? a : NEG_SLOPE * a;
    atomicAdd(&denom[d], expf(a - amax[d]));
}

__global__ __launch_bounds__(256) void emsg2_kernel(const int* __restrict__ ei,
    const float* __restrict__ a_s, const float* __restrict__ a_d,
    const float* __restrict__ amax, const float* __restrict__ denom,
    const float* __restrict__ h2, float* __restrict__ out2)
{
    int wid = blockIdx.x * 4 + (threadIdx.x >> 6);
    if (wid >= ET) return;
    int lane = threadIdx.x & 63;
    int s, d;
    if (wid < EE) { s = ei[wid]; d = ei[EE + wid]; } else { s = d = wid - EE; }
    float a = a_s[s] + a_d[d];
    a = (a > 0.f) ? a : NEG_SLOPE * a;
    float w = expf(a - amax[d]) / (denom[d] + 1e-16f);
    atomicAdd(&out2[(size_t)d * CC + lane], h2[(size_t)s * CC + lane] * w);
}

__global__ __launch_bounds__(256) void pool_kernel(const float* __restrict__ out2,
    const float* __restrict__ b2, const int* __restrict__ batch,
    float* __restrict__ pooled, float* __restrict__ cnt)
{
    int i = blockIdx.x * 256 + threadIdx.x;   // over N*64, grid exact
    if (i >= NN * CC) return;
    int n = i >> 6, c = i & 63;
    float v = out2[i] + b2[c];
    v = v > 0.f ? v : 0.f;
    int g = batch[n];
    atomicAdd(&pooled[g * CC + c], v);
    if (c == 0) atomicAdd(&cnt[g], 1.f);
}

__global__ void final_kernel(const float* __restrict__ pooled, const float* __restrict__ cnt,
    const float* __restrict__ fc_w, const float* __restrict__ fc_b, float* __restrict__ out)
{
    int g = blockIdx.x, lane = threadIdx.x;
    float v = pooled[g * CC + lane] / fmaxf(cnt[g], 1.f) * fc_w[lane];
    v = waveReduceSum(v);
    if (lane == 0) out[g] = v + fc_b[0];
}

extern "C" void kernel_launch(void* const* d_in, const int* in_sizes, int n_in,
                              void* d_out, int out_size, void* d_ws, size_t ws_size,
                              hipStream_t stream)
{
    const float* x        = (const float*)d_in[0];
    const float* W1       = (const float*)d_in[1];
    const float* att_src1 = (const float*)d_in[2];
    const float* att_dst1 = (const float*)d_in[3];
    const float* b1       = (const float*)d_in[4];
    const float* W2       = (const float*)d_in[5];
    const float* att_src2 = (const float*)d_in[6];
    const float* att_dst2 = (const float*)d_in[7];
    const float* b2       = (const float*)d_in[8];
    const float* fc_w     = (const float*)d_in[9];
    const float* fc_b     = (const float*)d_in[10];
    const int*   ei       = (const int*)d_in[11];   // [2, E] -> src = ei, dst = ei + EE
    const int*   batch    = (const int*)d_in[12];
    float* out = (float*)d_out;

    float* p = (float*)d_ws;
    float* h1     = p; p += (size_t)NN * HC;
    float* a_s1   = p; p += (size_t)NN * HH;
    float* a_d1   = p; p += (size_t)NN * HH;
    float* h2     = p; p += (size_t)NN * CC;
    float* a_s2   = p; p += NN;
    float* a_d2   = p; p += NN;
    float* amax1  = p; p += (size_t)NN * HH;   // -inf region starts here (amax1, amax2)
    float* amax2  = p; p += NN;
    float* denom1 = p; p += (size_t)NN * HH;   // zero region starts here
    float* denom2 = p; p += NN;
    float* out1   = p; p += (size_t)NN * HC;
    float* out2   = p; p += (size_t)NN * CC;
    float* pooled = p; p += (size_t)GG * CC;
    float* cnt    = p; p += GG;

    init_kernel<<<2048, 256, 0, stream>>>(amax1, denom1);
    gemm1_kernel<<<NN / 8, 256, 0, stream>>>(x, W1, att_src1, att_dst1, h1, a_s1, a_d1);
    emax1_kernel<<<(ET + 255) / 256, 256, 0, stream>>>(ei, a_s1, a_d1, amax1);
    esum1_kernel<<<(ET + 255) / 256, 256, 0, stream>>>(ei, a_s1, a_d1, amax1, denom1);
    emsg1_kernel<<<ET / 4, 256, 0, stream>>>(ei, a_s1, a_d1, amax1, denom1, h1, out1);
    gemm2_kernel<<<(NN + 31) / 32, 256, 0, stream>>>(out1, b1, W2, att_src2, att_dst2, h2, a_s2, a_d2);
    emax2_kernel<<<(ET + 255) / 256, 256, 0, stream>>>(ei, a_s2, a_d2, amax2);
    esum2_kernel<<<(ET + 255) / 256, 256, 0, stream>>>(ei, a_s2, a_d2, amax2, denom2);
    emsg2_kernel<<<ET / 4, 256, 0, stream>>>(ei, a_s2, a_d2, amax2, denom2, h2, out2);
    pool_kernel<<<(NN * CC) / 256, 256, 0, stream>>>(out2, b2, batch, pooled, cnt);
    final_kernel<<<GG, 64, 0, stream>>>(pooled, cnt, fc_w, fc_b, out);
}

// Round 2
// 630.456 us; speedup vs baseline: 2.4009x; 2.4009x over previous
//
#include <hip/hip_runtime.h>
#include <math.h>

#define NN 50000
#define FIN 128
#define HH 4
#define CC 64
#define HC (HH*CC)       // 256
#define GG 512
#define EE 800000
#define ET (EE + NN)     // 850000 edges incl. self-loops
#define NEG_SLOPE 0.2f

__device__ __forceinline__ float waveReduceSum(float v) {
    #pragma unroll
    for (int off = 32; off > 0; off >>= 1) v += __shfl_xor(v, off);
    return v;
}
__device__ __forceinline__ float waveReduceMax(float v) {
    #pragma unroll
    for (int off = 32; off > 0; off >>= 1) v = fmaxf(v, __shfl_xor(v, off));
    return v;
}

// zero counts / pooled / cnt (accumulated-into buffers; ws is not re-poisoned)
__global__ __launch_bounds__(256) void init0_kernel(int* __restrict__ counts,
                                                    float* __restrict__ pooled,
                                                    float* __restrict__ cnt) {
    int i = blockIdx.x * 256 + threadIdx.x;
    int stride = gridDim.x * 256;
    for (int j = i; j < NN; j += stride) counts[j] = 0;
    for (int j = i; j < GG * CC + GG; j += stride) pooled[j] = 0.f;  // pooled then cnt contiguous
}

__global__ __launch_bounds__(256) void hist_kernel(const int* __restrict__ ei,
                                                   int* __restrict__ counts) {
    int e = blockIdx.x * 256 + threadIdx.x;
    if (e >= ET) return;
    int d = (e < EE) ? ei[EE + e] : e - EE;
    atomicAdd(&counts[d], 1);
}

// single-block exclusive scan: counts[NN] -> rowptr[NN+1], cursor = rowptr
__global__ __launch_bounds__(1024) void scan_kernel(const int* __restrict__ counts,
                                                    int* __restrict__ rowptr,
                                                    int* __restrict__ cursor) {
    __shared__ int part[1024];
    const int t = threadIdx.x;
    const int CHK = (NN + 1023) / 1024;   // 49
    int base = t * CHK;
    int sum = 0;
    for (int i = 0; i < CHK; ++i) { int idx = base + i; if (idx < NN) sum += counts[idx]; }
    part[t] = sum;
    __syncthreads();
    for (int off = 1; off < 1024; off <<= 1) {
        int v = (t >= off) ? part[t - off] : 0;
        __syncthreads();
        part[t] += v;
        __syncthreads();
    }
    int run = (t == 0) ? 0 : part[t - 1];
    for (int i = 0; i < CHK; ++i) {
        int idx = base + i;
        if (idx < NN) { rowptr[idx] = run; cursor[idx] = run; run += counts[idx]; }
    }
    if (t == 1023) rowptr[NN] = run;   // = ET
}

__global__ __launch_bounds__(256) void fill_kernel(const int* __restrict__ ei,
                                                   int* __restrict__ cursor,
                                                   int* __restrict__ scsr) {
    int e = blockIdx.x * 256 + threadIdx.x;
    if (e >= ET) return;
    int s, d;
    if (e < EE) { s = ei[e]; d = ei[EE + e]; } else { s = d = e - EE; }
    int pos = atomicAdd(&cursor[d], 1);
    scsr[pos] = s;
}

__global__ __launch_bounds__(256) void cnt_kernel(const int* __restrict__ batch,
                                                  float* __restrict__ cnt) {
    int n = blockIdx.x * 256 + threadIdx.x;
    if (n >= NN) return;
    atomicAdd(&cnt[batch[n]], 1.f);
}

// h1 = x @ W1  [N,256]; fused a_s1/a_d1 [N,4]. 8 nodes per 256-thread block.
__global__ __launch_bounds__(256) void gemm1_kernel(
    const float* __restrict__ x, const float* __restrict__ W1,
    const float* __restrict__ att_src1, const float* __restrict__ att_dst1,
    float* __restrict__ h1, float* __restrict__ a_s1, float* __restrict__ a_d1)
{
    __shared__ float xs[8][FIN];
    int n0 = blockIdx.x * 8;
    int t = threadIdx.x;
    for (int i = t; i < 8 * FIN; i += 256) {
        int r = i >> 7, k = i & 127;
        xs[r][k] = x[(size_t)(n0 + r) * FIN + k];   // grid exact: 50000 = 6250*8
    }
    __syncthreads();
    float acc[8];
    #pragma unroll
    for (int r = 0; r < 8; ++r) acc[r] = 0.f;
    for (int k = 0; k < FIN; ++k) {
        float w = W1[k * HC + t];
        #pragma unroll
        for (int r = 0; r < 8; ++r) acc[r] += xs[r][k] * w;
    }
    int head = t >> 6, lane = t & 63;
    float asw = att_src1[head * CC + lane];
    float adw = att_dst1[head * CC + lane];
    #pragma unroll
    for (int r = 0; r < 8; ++r) {
        int n = n0 + r;
        h1[(size_t)n * HC + t] = acc[r];
        float vs = waveReduceSum(acc[r] * asw);
        float vd = waveReduceSum(acc[r] * adw);
        if (lane == 0) { a_s1[n * HH + head] = vs; a_d1[n * HH + head] = vd; }
    }
}

// per-dst softmax, layer 1: one 64-lane wave per dst node.
// writes ex (=exp(alpha-max)) into wcsr1[pos*4+h] and invden1[d*4+h].
__global__ __launch_bounds__(64) void attn1_kernel(
    const int* __restrict__ rowptr, const int* __restrict__ scsr,
    const float* __restrict__ a_s, const float* __restrict__ a_d,
    float* __restrict__ wcsr, float* __restrict__ invden)
{
    int d = blockIdx.x;
    int lane = threadIdx.x;
    int start = rowptr[d], end = rowptr[d + 1];
    float ad[HH];
    #pragma unroll
    for (int h = 0; h < HH; ++h) ad[h] = a_d[d * HH + h];
    float m[HH];
    #pragma unroll
    for (int h = 0; h < HH; ++h) m[h] = -INFINITY;
    for (int j = start + lane; j < end; j += 64) {
        int s = scsr[j];
        #pragma unroll
        for (int h = 0; h < HH; ++h) {
            float a = a_s[s * HH + h] + ad[h];
            a = (a > 0.f) ? a : NEG_SLOPE * a;
            m[h] = fmaxf(m[h], a);
        }
    }
    #pragma unroll
    for (int h = 0; h < HH; ++h) m[h] = waveReduceMax(m[h]);
    float den[HH];
    #pragma unroll
    for (int h = 0; h < HH; ++h) den[h] = 0.f;
    for (int j = start + lane; j < end; j += 64) {
        int s = scsr[j];
        #pragma unroll
        for (int h = 0; h < HH; ++h) {
            float a = a_s[s * HH + h] + ad[h];
            a = (a > 0.f) ? a : NEG_SLOPE * a;
            float ex = expf(a - m[h]);
            wcsr[(size_t)j * HH + h] = ex;
            den[h] += ex;
        }
    }
    #pragma unroll
    for (int h = 0; h < HH; ++h) den[h] = waveReduceSum(den[h]);
    if (lane == 0) {
        #pragma unroll
        for (int h = 0; h < HH; ++h) invden[d * HH + h] = 1.f / (den[h] + 1e-16f);
    }
}

// gather-accumulate, layer 1: one 256-thread block per dst node.
__global__ __launch_bounds__(256) void emsg1_gather_kernel(
    const int* __restrict__ rowptr, const int* __restrict__ scsr,
    const float* __restrict__ wcsr, const float* __restrict__ invden,
    const float* __restrict__ h1, float* __restrict__ out1)
{
    int d = blockIdx.x;
    int t = threadIdx.x;
    int head = t >> 6;
    int start = rowptr[d], end = rowptr[d + 1];
    float invd = invden[d * HH + head];
    float acc = 0.f;
    int j = start;
    for (; j + 1 < end; j += 2) {
        int s0 = scsr[j], s1 = scsr[j + 1];
        float w0 = wcsr[(size_t)j * HH + head];
        float w1 = wcsr[(size_t)(j + 1) * HH + head];
        float v0 = h1[(size_t)s0 * HC + t];
        float v1 = h1[(size_t)s1 * HC + t];
        acc += w0 * v0 + w1 * v1;
    }
    if (j < end) {
        int s0 = scsr[j];
        acc += wcsr[(size_t)j * HH + head] * h1[(size_t)s0 * HC + t];
    }
    out1[(size_t)d * HC + t] = acc * invd;
}

// h2 = relu(out1 + b1) @ W2  [N,64]; fused a_s2/a_d2. 32 nodes per block (4 waves x 8).
__global__ __launch_bounds__(256) void gemm2_kernel(
    const float* __restrict__ out1, const float* __restrict__ b1,
    const float* __restrict__ W2, const float* __restrict__ att_src2,
    const float* __restrict__ att_dst2,
    float* __restrict__ h2, float* __restrict__ a_s2, float* __restrict__ a_d2)
{
    __shared__ float xs[32][HC];
    int n0 = blockIdx.x * 32;
    int t = threadIdx.x;
    float bb = b1[t];
    for (int r = 0; r < 32; ++r) {
        int n = n0 + r;
        float v = (n < NN) ? out1[(size_t)n * HC + t] + bb : 0.f;
        xs[r][t] = v > 0.f ? v : 0.f;
    }
    __syncthreads();
    int wv = t >> 6, lane = t & 63;
    float acc[8];
    #pragma unroll
    for (int r = 0; r < 8; ++r) acc[r] = 0.f;
    for (int k = 0; k < HC; ++k) {
        float w = W2[k * CC + lane];
        #pragma unroll
        for (int r = 0; r < 8; ++r) acc[r] += xs[wv * 8 + r][k] * w;
    }
    float asw = att_src2[lane], adw = att_dst2[lane];
    #pragma unroll
    for (int r = 0; r < 8; ++r) {
        int n = n0 + wv * 8 + r;
        float vs = waveReduceSum(acc[r] * asw);
        float vd = waveReduceSum(acc[r] * adw);
        if (n < NN) {
            h2[(size_t)n * CC + lane] = acc[r];
            if (lane == 0) { a_s2[n] = vs; a_d2[n] = vd; }
        }
    }
}

// per-dst softmax, layer 2 (1 head): one wave per dst.
__global__ __launch_bounds__(64) void attn2_kernel(
    const int* __restrict__ rowptr, const int* __restrict__ scsr,
    const float* __restrict__ a_s, const float* __restrict__ a_d,
    float* __restrict__ wcsr, float* __restrict__ invden)
{
    int d = blockIdx.x;
    int lane = threadIdx.x;
    int start = rowptr[d], end = rowptr[d + 1];
    float ad = a_d[d];
    float m = -INFINITY;
    for (int j = start + lane; j < end; j += 64) {
        float a = a_s[scsr[j]] + ad;
        a = (a > 0.f) ? a : NEG_SLOPE * a;
        m = fmaxf(m, a);
    }
    m = waveReduceMax(m);
    float den = 0.f;
    for (int j = start + lane; j < end; j += 64) {
        float a = a_s[scsr[j]] + ad;
        a = (a > 0.f) ? a : NEG_SLOPE * a;
        float ex = expf(a - m);
        wcsr[j] = ex;
        den += ex;
    }
    den = waveReduceSum(den);
    if (lane == 0) invden[d] = 1.f / (den + 1e-16f);
}

// gather-accumulate layer 2 + fused relu/bias/mean-pool scatter. 1 wave per dst, 4/block.
__global__ __launch_bounds__(256) void emsg2_gather_kernel(
    const int* __restrict__ rowptr, const int* __restrict__ scsr,
    const float* __restrict__ wcsr, const float* __restrict__ invden,
    const float* __restrict__ h2, const float* __restrict__ b2,
    const int* __restrict__ batch, float* __restrict__ pooled)
{
    int d = blockIdx.x * 4 + (threadIdx.x >> 6);
    if (d >= NN) return;
    int lane = threadIdx.x & 63;
    int start = rowptr[d], end = rowptr[d + 1];
    float acc = 0.f;
    int j = start;
    for (; j + 1 < end; j += 2) {
        int s0 = scsr[j], s1 = scsr[j + 1];
        float w0 = wcsr[j], w1 = wcsr[j + 1];
        acc += w0 * h2[(size_t)s0 * CC + lane] + w1 * h2[(size_t)s1 * CC + lane];
    }
    if (j < end) acc += wcsr[j] * h2[(size_t)scsr[j] * CC + lane];
    float h = acc * invden[d] + b2[lane];
    h = h > 0.f ? h : 0.f;
    atomicAdd(&pooled[batch[d] * CC + lane], h);
}

__global__ void final_kernel(const float* __restrict__ pooled, const float* __restrict__ cnt,
    const float* __restrict__ fc_w, const float* __restrict__ fc_b, float* __restrict__ out)
{
    int g = blockIdx.x, lane = threadIdx.x;
    float v = pooled[g * CC + lane] / fmaxf(cnt[g], 1.f) * fc_w[lane];
    v = waveReduceSum(v);
    if (lane == 0) out[g] = v + fc_b[0];
}

extern "C" void kernel_launch(void* const* d_in, const int* in_sizes, int n_in,
                              void* d_out, int out_size, void* d_ws, size_t ws_size,
                              hipStream_t stream)
{
    const float* x        = (const float*)d_in[0];
    const float* W1       = (const float*)d_in[1];
    const float* att_src1 = (const float*)d_in[2];
    const float* att_dst1 = (const float*)d_in[3];
    const float* b1       = (const float*)d_in[4];
    const float* W2       = (const float*)d_in[5];
    const float* att_src2 = (const float*)d_in[6];
    const float* att_dst2 = (const float*)d_in[7];
    const float* b2       = (const float*)d_in[8];
    const float* fc_w     = (const float*)d_in[9];
    const float* fc_b     = (const float*)d_in[10];
    const int*   ei       = (const int*)d_in[11];   // [2, E] -> src = ei, dst = ei + EE
    const int*   batch    = (const int*)d_in[12];
    float* out = (float*)d_out;

    float* p = (float*)d_ws;
    float* h1      = p; p += (size_t)NN * HC;     // 12.8M  (layer-2 arrays overlay here later)
    float* a_s1    = p; p += (size_t)NN * HH;
    float* a_d1    = p; p += (size_t)NN * HH;
    float* invden1 = p; p += (size_t)NN * HH;
    float* wcsr1   = p; p += (size_t)ET * HH;     // 3.4M
    float* out1    = p; p += (size_t)NN * HC;     // 12.8M
    float* wcsr2   = p; p += (size_t)ET;
    float* a_s2    = p; p += NN;
    float* a_d2    = p; p += NN;
    float* invden2 = p; p += NN;
    float* pooled  = p; p += (size_t)GG * CC;     // pooled and cnt contiguous (init0 zeroes both)
    float* cnt     = p; p += GG;
    int*   counts  = (int*)p; p += NN;
    int*   rowptr  = (int*)p; p += NN + 1;
    int*   cursor  = (int*)p; p += NN;
    int*   scsr    = (int*)p; p += ET;
    float* h2      = h1;                          // overlay: h1 dead after emsg1_gather

    const int EB = (ET + 255) / 256;

    init0_kernel<<<256, 256, 0, stream>>>(counts, pooled, cnt);
    hist_kernel<<<EB, 256, 0, stream>>>(ei, counts);
    cnt_kernel<<<(NN + 255) / 256, 256, 0, stream>>>(batch, cnt);
    scan_kernel<<<1, 1024, 0, stream>>>(counts, rowptr, cursor);
    fill_kernel<<<EB, 256, 0, stream>>>(ei, cursor, scsr);
    gemm1_kernel<<<NN / 8, 256, 0, stream>>>(x, W1, att_src1, att_dst1, h1, a_s1, a_d1);
    attn1_kernel<<<NN, 64, 0, stream>>>(rowptr, scsr, a_s1, a_d1, wcsr1, invden1);
    emsg1_gather_kernel<<<NN, 256, 0, stream>>>(rowptr, scsr, wcsr1, invden1, h1, out1);
    gemm2_kernel<<<(NN + 31) / 32, 256, 0, stream>>>(out1, b1, W2, att_src2, att_dst2, h2, a_s2, a_d2);
    attn2_kernel<<<NN, 64, 0, stream>>>(rowptr, scsr, a_s2, a_d2, wcsr2, invden2);
    emsg2_gather_kernel<<<(NN + 3) / 4, 256, 0, stream>>>(rowptr, scsr, wcsr2, invden2, h2, b2, batch, pooled);
    final_kernel<<<GG, 64, 0, stream>>>(pooled, cnt, fc_w, fc_b, out);
}

// Round 3
// 619.769 us; speedup vs baseline: 2.4423x; 1.0172x over previous
//
#include <hip/hip_runtime.h>
#include <hip/hip_fp16.h>
#include <math.h>

#define NN 50000
#define FIN 128
#define HH 4
#define CC 64
#define HC (HH*CC)       // 256
#define GG 512
#define EE 800000
#define ET (EE + NN)     // 850000 edges incl. self-loops
#define NEG_SLOPE 0.2f

__device__ __forceinline__ float waveReduceSum(float v) {
    #pragma unroll
    for (int off = 32; off > 0; off >>= 1) v += __shfl_xor(v, off);
    return v;
}
__device__ __forceinline__ float waveReduceMax(float v) {
    #pragma unroll
    for (int off = 32; off > 0; off >>= 1) v = fmaxf(v, __shfl_xor(v, off));
    return v;
}

// zero counts / pooled / cnt (accumulated-into buffers; ws is not re-poisoned)
__global__ __launch_bounds__(256) void init0_kernel(int* __restrict__ counts,
                                                    float* __restrict__ pooled) {
    int i = blockIdx.x * 256 + threadIdx.x;
    int stride = gridDim.x * 256;
    for (int j = i; j < NN; j += stride) counts[j] = 0;
    for (int j = i; j < GG * CC + GG; j += stride) pooled[j] = 0.f;  // pooled then cnt contiguous
}

__global__ __launch_bounds__(256) void hist_kernel(const int* __restrict__ ei,
                                                   int* __restrict__ counts) {
    int e = blockIdx.x * 256 + threadIdx.x;
    if (e >= ET) return;
    int d = (e < EE) ? ei[EE + e] : e - EE;
    atomicAdd(&counts[d], 1);
}

// single-block exclusive scan: counts[NN] -> rowptr[NN+1], cursor = rowptr
__global__ __launch_bounds__(1024) void scan_kernel(const int* __restrict__ counts,
                                                    int* __restrict__ rowptr,
                                                    int* __restrict__ cursor) {
    __shared__ int part[1024];
    const int t = threadIdx.x;
    const int CHK = (NN + 1023) / 1024;   // 49
    int base = t * CHK;
    int sum = 0;
    for (int i = 0; i < CHK; ++i) { int idx = base + i; if (idx < NN) sum += counts[idx]; }
    part[t] = sum;
    __syncthreads();
    for (int off = 1; off < 1024; off <<= 1) {
        int v = (t >= off) ? part[t - off] : 0;
        __syncthreads();
        part[t] += v;
        __syncthreads();
    }
    int run = (t == 0) ? 0 : part[t - 1];
    for (int i = 0; i < CHK; ++i) {
        int idx = base + i;
        if (idx < NN) { rowptr[idx] = run; cursor[idx] = run; run += counts[idx]; }
    }
    if (t == 1023) rowptr[NN] = run;   // = ET
}

__global__ __launch_bounds__(256) void fill_kernel(const int* __restrict__ ei,
                                                   int* __restrict__ cursor,
                                                   int* __restrict__ scsr) {
    int e = blockIdx.x * 256 + threadIdx.x;
    if (e >= ET) return;
    int s, d;
    if (e < EE) { s = ei[e]; d = ei[EE + e]; } else { s = d = e - EE; }
    int pos = atomicAdd(&cursor[d], 1);
    scsr[pos] = s;
}

__global__ __launch_bounds__(256) void cnt_kernel(const int* __restrict__ batch,
                                                  float* __restrict__ cnt) {
    int n = blockIdx.x * 256 + threadIdx.x;
    if (n >= NN) return;
    atomicAdd(&cnt[batch[n]], 1.f);
}

// h1 = x @ W1  [N,256] (stored fp16); fused a_s1/a_d1 [N,4]. 8 nodes per block.
__global__ __launch_bounds__(256) void gemm1_kernel(
    const float* __restrict__ x, const float* __restrict__ W1,
    const float* __restrict__ att_src1, const float* __restrict__ att_dst1,
    __half* __restrict__ h1, float* __restrict__ a_s1, float* __restrict__ a_d1)
{
    __shared__ __align__(16) float xs[8][FIN];
    int n0 = blockIdx.x * 8;
    int t = threadIdx.x;
    for (int i = t; i < 8 * FIN; i += 256) {
        int r = i >> 7, k = i & 127;
        xs[r][k] = x[(size_t)(n0 + r) * FIN + k];   // grid exact: 50000 = 6250*8
    }
    __syncthreads();
    float acc[8];
    #pragma unroll
    for (int r = 0; r < 8; ++r) acc[r] = 0.f;
    for (int k = 0; k < FIN; k += 4) {
        float4 xv[8];
        #pragma unroll
        for (int r = 0; r < 8; ++r) xv[r] = *(const float4*)&xs[r][k];
        #pragma unroll
        for (int i = 0; i < 4; ++i) {
            float w = W1[(size_t)(k + i) * HC + t];
            #pragma unroll
            for (int r = 0; r < 8; ++r)
                acc[r] += ((const float*)&xv[r])[i] * w;
        }
    }
    int head = t >> 6, lane = t & 63;
    float asw = att_src1[head * CC + lane];
    float adw = att_dst1[head * CC + lane];
    #pragma unroll
    for (int r = 0; r < 8; ++r) {
        int n = n0 + r;
        h1[(size_t)n * HC + t] = __float2half(acc[r]);
        float vs = waveReduceSum(acc[r] * asw);
        float vd = waveReduceSum(acc[r] * adw);
        if (lane == 0) { a_s1[n * HH + head] = vs; a_d1[n * HH + head] = vd; }
    }
}

// fused softmax + gather-accumulate, layer 1: one 256-thread block per dst.
// head-wave computes its own max, then serial edge loop with inline exp.
__global__ __launch_bounds__(256) void emsg1_fused_kernel(
    const int* __restrict__ rowptr, const int* __restrict__ scsr,
    const float* __restrict__ a_s, const float* __restrict__ a_d,
    const __half* __restrict__ h1, float* __restrict__ out1)
{
    int d = blockIdx.x;
    int t = threadIdx.x;
    int head = t >> 6, lane = t & 63;
    int start = rowptr[d], end = rowptr[d + 1];
    float ad = a_d[d * HH + head];
    // pass 1: per-head max over incoming edges
    float m = -INFINITY;
    for (int j = start + lane; j < end; j += 64) {
        float a = a_s[scsr[j] * HH + head] + ad;
        a = (a > 0.f) ? a : NEG_SLOPE * a;
        m = fmaxf(m, a);
    }
    m = waveReduceMax(m);
    // pass 2: serial edges; exp computed broadcast-redundantly per lane
    float den = 0.f, acc = 0.f;
    int j = start;
    for (; j + 1 < end; j += 2) {
        int s0 = scsr[j], s1 = scsr[j + 1];
        float a0 = a_s[s0 * HH + head] + ad;
        float a1 = a_s[s1 * HH + head] + ad;
        a0 = (a0 > 0.f) ? a0 : NEG_SLOPE * a0;
        a1 = (a1 > 0.f) ? a1 : NEG_SLOPE * a1;
        float w0 = expf(a0 - m), w1 = expf(a1 - m);
        float v0 = __half2float(h1[(size_t)s0 * HC + t]);
        float v1 = __half2float(h1[(size_t)s1 * HC + t]);
        acc += w0 * v0 + w1 * v1;
        den += w0 + w1;
    }
    if (j < end) {
        int s0 = scsr[j];
        float a0 = a_s[s0 * HH + head] + ad;
        a0 = (a0 > 0.f) ? a0 : NEG_SLOPE * a0;
        float w0 = expf(a0 - m);
        acc += w0 * __half2float(h1[(size_t)s0 * HC + t]);
        den += w0;
    }
    out1[(size_t)d * HC + t] = acc / (den + 1e-16f);
}

// h2 = relu(out1 + b1) @ W2  [N,64] (stored fp16); fused a_s2/a_d2.
__global__ __launch_bounds__(256) void gemm2_kernel(
    const float* __restrict__ out1, const float* __restrict__ b1,
    const float* __restrict__ W2, const float* __restrict__ att_src2,
    const float* __restrict__ att_dst2,
    __half* __restrict__ h2, float* __restrict__ a_s2, float* __restrict__ a_d2)
{
    __shared__ __align__(16) float xs[32][HC];
    int n0 = blockIdx.x * 32;
    int t = threadIdx.x;
    float bb = b1[t];
    for (int r = 0; r < 32; ++r) {
        int n = n0 + r;
        float v = (n < NN) ? out1[(size_t)n * HC + t] + bb : 0.f;
        xs[r][t] = v > 0.f ? v : 0.f;
    }
    __syncthreads();
    int wv = t >> 6, lane = t & 63;
    float acc[8];
    #pragma unroll
    for (int r = 0; r < 8; ++r) acc[r] = 0.f;
    for (int k = 0; k < HC; k += 4) {
        float4 xv[8];
        #pragma unroll
        for (int r = 0; r < 8; ++r) xv[r] = *(const float4*)&xs[wv * 8 + r][k];
        #pragma unroll
        for (int i = 0; i < 4; ++i) {
            float w = W2[(size_t)(k + i) * CC + lane];
            #pragma unroll
            for (int r = 0; r < 8; ++r)
                acc[r] += ((const float*)&xv[r])[i] * w;
        }
    }
    float asw = att_src2[lane], adw = att_dst2[lane];
    #pragma unroll
    for (int r = 0; r < 8; ++r) {
        int n = n0 + wv * 8 + r;
        float vs = waveReduceSum(acc[r] * asw);
        float vd = waveReduceSum(acc[r] * adw);
        if (n < NN) {
            h2[(size_t)n * CC + lane] = __float2half(acc[r]);
            if (lane == 0) { a_s2[n] = vs; a_d2[n] = vd; }
        }
    }
}

// fused softmax + gather layer 2 + relu/bias/mean-pool scatter. 1 wave/dst, 4 per block.
__global__ __launch_bounds__(256) void emsg2_fused_kernel(
    const int* __restrict__ rowptr, const int* __restrict__ scsr,
    const float* __restrict__ a_s, const float* __restrict__ a_d,
    const __half* __restrict__ h2, const float* __restrict__ b2,
    const int* __restrict__ batch, float* __restrict__ pooled)
{
    int d = blockIdx.x * 4 + (threadIdx.x >> 6);
    if (d >= NN) return;
    int lane = threadIdx.x & 63;
    int start = rowptr[d], end = rowptr[d + 1];
    float ad = a_d[d];
    float m = -INFINITY;
    for (int j = start + lane; j < end; j += 64) {
        float a = a_s[scsr[j]] + ad;
        a = (a > 0.f) ? a : NEG_SLOPE * a;
        m = fmaxf(m, a);
    }
    m = waveReduceMax(m);
    float den = 0.f, acc = 0.f;
    int j = start;
    for (; j + 1 < end; j += 2) {
        int s0 = scsr[j], s1 = scsr[j + 1];
        float a0 = a_s[s0] + ad;
        float a1 = a_s[s1] + ad;
        a0 = (a0 > 0.f) ? a0 : NEG_SLOPE * a0;
        a1 = (a1 > 0.f) ? a1 : NEG_SLOPE * a1;
        float w0 = expf(a0 - m), w1 = expf(a1 - m);
        acc += w0 * __half2float(h2[(size_t)s0 * CC + lane])
             + w1 * __half2float(h2[(size_t)s1 * CC + lane]);
        den += w0 + w1;
    }
    if (j < end) {
        int s0 = scsr[j];
        float a0 = a_s[s0] + ad;
        a0 = (a0 > 0.f) ? a0 : NEG_SLOPE * a0;
        float w0 = expf(a0 - m);
        acc += w0 * __half2float(h2[(size_t)s0 * CC + lane]);
        den += w0;
    }
    float h = acc / (den + 1e-16f) + b2[lane];
    h = h > 0.f ? h : 0.f;
    atomicAdd(&pooled[batch[d] * CC + lane], h);
}

__global__ void final_kernel(const float* __restrict__ pooled, const float* __restrict__ cnt,
    const float* __restrict__ fc_w, const float* __restrict__ fc_b, float* __restrict__ out)
{
    int g = blockIdx.x, lane = threadIdx.x;
    float v = pooled[g * CC + lane] / fmaxf(cnt[g], 1.f) * fc_w[lane];
    v = waveReduceSum(v);
    if (lane == 0) out[g] = v + fc_b[0];
}

extern "C" void kernel_launch(void* const* d_in, const int* in_sizes, int n_in,
                              void* d_out, int out_size, void* d_ws, size_t ws_size,
                              hipStream_t stream)
{
    const float* x        = (const float*)d_in[0];
    const float* W1       = (const float*)d_in[1];
    const float* att_src1 = (const float*)d_in[2];
    const float* att_dst1 = (const float*)d_in[3];
    const float* b1       = (const float*)d_in[4];
    const float* W2       = (const float*)d_in[5];
    const float* att_src2 = (const float*)d_in[6];
    const float* att_dst2 = (const float*)d_in[7];
    const float* b2       = (const float*)d_in[8];
    const float* fc_w     = (const float*)d_in[9];
    const float* fc_b     = (const float*)d_in[10];
    const int*   ei       = (const int*)d_in[11];   // [2, E] -> src = ei, dst = ei + EE
    const int*   batch    = (const int*)d_in[12];
    float* out = (float*)d_out;

    char* p = (char*)d_ws;
    __half* h1   = (__half*)p; p += (size_t)NN * HC * sizeof(__half);   // 25.6 MB
    __half* h2   = (__half*)p; p += (size_t)NN * CC * sizeof(__half);   // 6.4 MB
    float* a_s1  = (float*)p;  p += (size_t)NN * HH * sizeof(float);
    float* a_d1  = (float*)p;  p += (size_t)NN * HH * sizeof(float);
    float* a_s2  = (float*)p;  p += NN * sizeof(float);
    float* a_d2  = (float*)p;  p += NN * sizeof(float);
    float* out1  = (float*)p;  p += (size_t)NN * HC * sizeof(float);    // 51.2 MB
    float* pooled= (float*)p;  p += (size_t)GG * CC * sizeof(float);    // pooled+cnt contiguous
    float* cnt   = (float*)p;  p += GG * sizeof(float);
    int* counts  = (int*)p;    p += NN * sizeof(int);
    int* rowptr  = (int*)p;    p += (NN + 1) * sizeof(int);
    int* cursor  = (int*)p;    p += NN * sizeof(int);
    int* scsr    = (int*)p;    p += ET * sizeof(int);

    const int EB = (ET + 255) / 256;

    init0_kernel<<<256, 256, 0, stream>>>(counts, pooled);
    hist_kernel<<<EB, 256, 0, stream>>>(ei, counts);
    cnt_kernel<<<(NN + 255) / 256, 256, 0, stream>>>(batch, cnt);
    scan_kernel<<<1, 1024, 0, stream>>>(counts, rowptr, cursor);
    fill_kernel<<<EB, 256, 0, stream>>>(ei, cursor, scsr);
    gemm1_kernel<<<NN / 8, 256, 0, stream>>>(x, W1, att_src1, att_dst1, h1, a_s1, a_d1);
    emsg1_fused_kernel<<<NN, 256, 0, stream>>>(rowptr, scsr, a_s1, a_d1, h1, out1);
    gemm2_kernel<<<(NN + 31) / 32, 256, 0, stream>>>(out1, b1, W2, att_src2, att_dst2, h2, a_s2, a_d2);
    emsg2_fused_kernel<<<(NN + 3) / 4, 256, 0, stream>>>(rowptr, scsr, a_s2, a_d2, h2, b2, batch, pooled);
    final_kernel<<<GG, 64, 0, stream>>>(pooled, cnt, fc_w, fc_b, out);
}

// Round 4
// 586.597 us; speedup vs baseline: 2.5804x; 1.0565x over previous
//
#include <hip/hip_runtime.h>
#include <hip/hip_fp16.h>
#include <math.h>

#define NN 50000
#define FIN 128
#define HH 4
#define CC 64
#define HC (HH*CC)       // 256
#define GG 512
#define EE 800000
#define ET (EE + NN)     // 850000 edges incl. self-loops
#define NEG_SLOPE 0.2f

__device__ __forceinline__ float waveReduceSum(float v) {
    #pragma unroll
    for (int off = 32; off > 0; off >>= 1) v += __shfl_xor(v, off);
    return v;
}

// zero counts / pooled / cnt (accumulated-into buffers; ws is not re-poisoned)
__global__ __launch_bounds__(256) void init0_kernel(int* __restrict__ counts,
                                                    float* __restrict__ pooled) {
    int i = blockIdx.x * 256 + threadIdx.x;
    int stride = gridDim.x * 256;
    for (int j = i; j < NN; j += stride) counts[j] = 0;
    for (int j = i; j < GG * CC + GG; j += stride) pooled[j] = 0.f;  // pooled then cnt contiguous
}

// histogram of dst + batch count, fused
__global__ __launch_bounds__(256) void histcnt_kernel(const int* __restrict__ ei,
                                                      int* __restrict__ counts,
                                                      const int* __restrict__ batch,
                                                      float* __restrict__ cnt) {
    int e = blockIdx.x * 256 + threadIdx.x;
    if (e < ET) {
        int d = (e < EE) ? ei[EE + e] : e - EE;
        atomicAdd(&counts[d], 1);
    }
    if (e < NN) atomicAdd(&cnt[batch[e]], 1.f);
}

// single-block exclusive scan: counts[NN] -> rowptr[NN+1], cursor = rowptr
__global__ __launch_bounds__(1024) void scan_kernel(const int* __restrict__ counts,
                                                    int* __restrict__ rowptr,
                                                    int* __restrict__ cursor) {
    __shared__ int part[1024];
    const int t = threadIdx.x;
    const int CHK = (NN + 1023) / 1024;   // 49
    int base = t * CHK;
    int sum = 0;
    for (int i = 0; i < CHK; ++i) { int idx = base + i; if (idx < NN) sum += counts[idx]; }
    part[t] = sum;
    __syncthreads();
    for (int off = 1; off < 1024; off <<= 1) {
        int v = (t >= off) ? part[t - off] : 0;
        __syncthreads();
        part[t] += v;
        __syncthreads();
    }
    int run = (t == 0) ? 0 : part[t - 1];
    for (int i = 0; i < CHK; ++i) {
        int idx = base + i;
        if (idx < NN) { rowptr[idx] = run; cursor[idx] = run; run += counts[idx]; }
    }
    if (t == 1023) rowptr[NN] = run;   // = ET
}

__global__ __launch_bounds__(256) void fill_kernel(const int* __restrict__ ei,
                                                   int* __restrict__ cursor,
                                                   int* __restrict__ scsr) {
    int e = blockIdx.x * 256 + threadIdx.x;
    if (e >= ET) return;
    int s, d;
    if (e < EE) { s = ei[e]; d = ei[EE + e]; } else { s = d = e - EE; }
    int pos = atomicAdd(&cursor[d], 1);
    scsr[pos] = s;
}

// h1 = x @ W1  [N,256] (stored fp16); fused a_s1/a_d1 [N,4]. 8 nodes per block.
__global__ __launch_bounds__(256) void gemm1_kernel(
    const float* __restrict__ x, const float* __restrict__ W1,
    const float* __restrict__ att_src1, const float* __restrict__ att_dst1,
    __half* __restrict__ h1, float* __restrict__ a_s1, float* __restrict__ a_d1)
{
    __shared__ __align__(16) float xs[8][FIN];
    int n0 = blockIdx.x * 8;
    int t = threadIdx.x;
    for (int i = t; i < 8 * FIN; i += 256) {
        int r = i >> 7, k = i & 127;
        xs[r][k] = x[(size_t)(n0 + r) * FIN + k];   // grid exact: 50000 = 6250*8
    }
    __syncthreads();
    float acc[8];
    #pragma unroll
    for (int r = 0; r < 8; ++r) acc[r] = 0.f;
    for (int k = 0; k < FIN; k += 4) {
        float4 xv[8];
        #pragma unroll
        for (int r = 0; r < 8; ++r) xv[r] = *(const float4*)&xs[r][k];
        #pragma unroll
        for (int i = 0; i < 4; ++i) {
            float w = W1[(size_t)(k + i) * HC + t];
            #pragma unroll
            for (int r = 0; r < 8; ++r)
                acc[r] += ((const float*)&xv[r])[i] * w;
        }
    }
    int head = t >> 6, lane = t & 63;
    float asw = att_src1[head * CC + lane];
    float adw = att_dst1[head * CC + lane];
    #pragma unroll
    for (int r = 0; r < 8; ++r) {
        int n = n0 + r;
        h1[(size_t)n * HC + t] = __float2half(acc[r]);
        float vs = waveReduceSum(acc[r] * asw);
        float vd = waveReduceSum(acc[r] * adw);
        if (lane == 0) { a_s1[n * HH + head] = vs; a_d1[n * HH + head] = vd; }
    }
}

// per-dst edge-lane-parallel weights, layer 1. wave per dst, 4 dst/block.
// no max-subtraction: |alpha| ~ O(1), exp() safe; softmax shift-invariant.
__global__ __launch_bounds__(256) void attn1_kernel(
    const int* __restrict__ rowptr, const int* __restrict__ scsr,
    const float4* __restrict__ a_s4, const float4* __restrict__ a_d4,
    float4* __restrict__ wcsr4, float4* __restrict__ invden4)
{
    int d = blockIdx.x * 4 + (threadIdx.x >> 6);   // grid exact: 12500*4
    int lane = threadIdx.x & 63;
    int start = rowptr[d], end = rowptr[d + 1];
    float4 ad = a_d4[d];
    float den0 = 0.f, den1 = 0.f, den2 = 0.f, den3 = 0.f;
    for (int j = start + lane; j < end; j += 64) {
        float4 as = a_s4[scsr[j]];
        float a0 = as.x + ad.x, a1 = as.y + ad.y, a2 = as.z + ad.z, a3 = as.w + ad.w;
        a0 = (a0 > 0.f) ? a0 : NEG_SLOPE * a0;
        a1 = (a1 > 0.f) ? a1 : NEG_SLOPE * a1;
        a2 = (a2 > 0.f) ? a2 : NEG_SLOPE * a2;
        a3 = (a3 > 0.f) ? a3 : NEG_SLOPE * a3;
        float w0 = expf(a0), w1 = expf(a1), w2 = expf(a2), w3 = expf(a3);
        wcsr4[j] = make_float4(w0, w1, w2, w3);
        den0 += w0; den1 += w1; den2 += w2; den3 += w3;
    }
    den0 = waveReduceSum(den0);
    den1 = waveReduceSum(den1);
    den2 = waveReduceSum(den2);
    den3 = waveReduceSum(den3);
    if (lane == 0)
        invden4[d] = make_float4(1.f / (den0 + 1e-16f), 1.f / (den1 + 1e-16f),
                                 1.f / (den2 + 1e-16f), 1.f / (den3 + 1e-16f));
}

// pure gather-accumulate, layer 1: 2 dst per 256-thread block, half2 payload.
__global__ __launch_bounds__(256) void emsg1_gather_kernel(
    const int* __restrict__ rowptr, const int* __restrict__ scsr,
    const float* __restrict__ wcsr, const float* __restrict__ invden,
    const __half2* __restrict__ h1, float2* __restrict__ out1)
{
    int t = threadIdx.x;
    int g = t >> 7;            // which dst in block
    int u = t & 127;           // channel-pair index (2u, 2u+1)
    int d = blockIdx.x * 2 + g;   // grid exact: 25000*2
    int head = u >> 5;
    int start = rowptr[d], end = rowptr[d + 1];
    float ax = 0.f, ay = 0.f;
    int j = start;
    for (; j + 1 < end; j += 2) {
        int s0 = scsr[j], s1 = scsr[j + 1];
        float w0 = wcsr[j * 4 + head];
        float w1 = wcsr[(j + 1) * 4 + head];
        float2 v0 = __half22float2(h1[(size_t)s0 * 128 + u]);
        float2 v1 = __half22float2(h1[(size_t)s1 * 128 + u]);
        ax += w0 * v0.x + w1 * v1.x;
        ay += w0 * v0.y + w1 * v1.y;
    }
    if (j < end) {
        int s0 = scsr[j];
        float w0 = wcsr[j * 4 + head];
        float2 v0 = __half22float2(h1[(size_t)s0 * 128 + u]);
        ax += w0 * v0.x;
        ay += w0 * v0.y;
    }
    float inv = invden[d * 4 + head];
    out1[(size_t)d * 128 + u] = make_float2(ax * inv, ay * inv);
}

// h2 = relu(out1 + b1) @ W2  [N,64] f32; fused a_s2/a_d2. 32 nodes per block.
__global__ __launch_bounds__(256) void gemm2_kernel(
    const float* __restrict__ out1, const float* __restrict__ b1,
    const float* __restrict__ W2, const float* __restrict__ att_src2,
    const float* __restrict__ att_dst2,
    float* __restrict__ h2, float* __restrict__ a_s2, float* __restrict__ a_d2)
{
    __shared__ __align__(16) float xs[32][HC];
    int n0 = blockIdx.x * 32;
    int t = threadIdx.x;
    float bb = b1[t];
    for (int r = 0; r < 32; ++r) {
        int n = n0 + r;
        float v = (n < NN) ? out1[(size_t)n * HC + t] + bb : 0.f;
        xs[r][t] = v > 0.f ? v : 0.f;
    }
    __syncthreads();
    int wv = t >> 6, lane = t & 63;
    float acc[8];
    #pragma unroll
    for (int r = 0; r < 8; ++r) acc[r] = 0.f;
    for (int k = 0; k < HC; k += 4) {
        float4 xv[8];
        #pragma unroll
        for (int r = 0; r < 8; ++r) xv[r] = *(const float4*)&xs[wv * 8 + r][k];
        #pragma unroll
        for (int i = 0; i < 4; ++i) {
            float w = W2[(size_t)(k + i) * CC + lane];
            #pragma unroll
            for (int r = 0; r < 8; ++r)
                acc[r] += ((const float*)&xv[r])[i] * w;
        }
    }
    float asw = att_src2[lane], adw = att_dst2[lane];
    #pragma unroll
    for (int r = 0; r < 8; ++r) {
        int n = n0 + wv * 8 + r;
        float vs = waveReduceSum(acc[r] * asw);
        float vd = waveReduceSum(acc[r] * adw);
        if (n < NN) {
            h2[(size_t)n * CC + lane] = acc[r];
            if (lane == 0) { a_s2[n] = vs; a_d2[n] = vd; }
        }
    }
}

// per-dst edge-lane-parallel weights, layer 2 (1 head). wave per dst, 4/block.
__global__ __launch_bounds__(256) void attn2_kernel(
    const int* __restrict__ rowptr, const int* __restrict__ scsr,
    const float* __restrict__ a_s, const float* __restrict__ a_d,
    float* __restrict__ wcsr, float* __restrict__ invden)
{
    int d = blockIdx.x * 4 + (threadIdx.x >> 6);
    int lane = threadIdx.x & 63;
    int start = rowptr[d], end = rowptr[d + 1];
    float ad = a_d[d];
    float den = 0.f;
    for (int j = start + lane; j < end; j += 64) {
        float a = a_s[scsr[j]] + ad;
        a = (a > 0.f) ? a : NEG_SLOPE * a;
        float w = expf(a);
        wcsr[j] = w;
        den += w;
    }
    den = waveReduceSum(den);
    if (lane == 0) invden[d] = 1.f / (den + 1e-16f);
}

// pure gather layer 2 + fused relu/bias/mean-pool scatter. 1 wave/dst, 4/block.
__global__ __launch_bounds__(256) void emsg2_gather_kernel(
    const int* __restrict__ rowptr, const int* __restrict__ scsr,
    const float* __restrict__ wcsr, const float* __restrict__ invden,
    const float* __restrict__ h2, const float* __restrict__ b2,
    const int* __restrict__ batch, float* __restrict__ pooled)
{
    int d = blockIdx.x * 4 + (threadIdx.x >> 6);
    int lane = threadIdx.x & 63;
    int start = rowptr[d], end = rowptr[d + 1];
    float acc = 0.f;
    int j = start;
    for (; j + 1 < end; j += 2) {
        int s0 = scsr[j], s1 = scsr[j + 1];
        float w0 = wcsr[j], w1 = wcsr[j + 1];
        acc += w0 * h2[(size_t)s0 * CC + lane] + w1 * h2[(size_t)s1 * CC + lane];
    }
    if (j < end) acc += wcsr[j] * h2[(size_t)scsr[j] * CC + lane];
    float h = acc * invden[d] + b2[lane];
    h = h > 0.f ? h : 0.f;
    atomicAdd(&pooled[batch[d] * CC + lane], h);
}

__global__ void final_kernel(const float* __restrict__ pooled, const float* __restrict__ cnt,
    const float* __restrict__ fc_w, const float* __restrict__ fc_b, float* __restrict__ out)
{
    int g = blockIdx.x, lane = threadIdx.x;
    float v = pooled[g * CC + lane] / fmaxf(cnt[g], 1.f) * fc_w[lane];
    v = waveReduceSum(v);
    if (lane == 0) out[g] = v + fc_b[0];
}

extern "C" void kernel_launch(void* const* d_in, const int* in_sizes, int n_in,
                              void* d_out, int out_size, void* d_ws, size_t ws_size,
                              hipStream_t stream)
{
    const float* x        = (const float*)d_in[0];
    const float* W1       = (const float*)d_in[1];
    const float* att_src1 = (const float*)d_in[2];
    const float* att_dst1 = (const float*)d_in[3];
    const float* b1       = (const float*)d_in[4];
    const float* W2       = (const float*)d_in[5];
    const float* att_src2 = (const float*)d_in[6];
    const float* att_dst2 = (const float*)d_in[7];
    const float* b2       = (const float*)d_in[8];
    const float* fc_w     = (const float*)d_in[9];
    const float* fc_b     = (const float*)d_in[10];
    const int*   ei       = (const int*)d_in[11];   // [2, E] -> src = ei, dst = ei + EE
    const int*   batch    = (const int*)d_in[12];
    float* out = (float*)d_out;

    char* p = (char*)d_ws;
    __half* h1    = (__half*)p; p += (size_t)NN * HC * sizeof(__half);   // 25.6 MB
    float* out1   = (float*)p;  p += (size_t)NN * HC * sizeof(float);    // 51.2 MB
    float* h2     = (float*)p;  p += (size_t)NN * CC * sizeof(float);    // 12.8 MB
    float* wcsr1  = (float*)p;  p += (size_t)ET * HH * sizeof(float);    // 13.6 MB
    float* wcsr2  = (float*)p;  p += (size_t)ET * sizeof(float);         // 3.4 MB
    float* a_s1   = (float*)p;  p += (size_t)NN * HH * sizeof(float);
    float* a_d1   = (float*)p;  p += (size_t)NN * HH * sizeof(float);
    float* invden1= (float*)p;  p += (size_t)NN * HH * sizeof(float);
    float* a_s2   = (float*)p;  p += NN * sizeof(float);
    float* a_d2   = (float*)p;  p += NN * sizeof(float);
    float* invden2= (float*)p;  p += NN * sizeof(float);
    float* pooled = (float*)p;  p += (size_t)GG * CC * sizeof(float);    // pooled+cnt contiguous
    float* cnt    = (float*)p;  p += GG * sizeof(float);
    int* counts   = (int*)p;    p += NN * sizeof(int);
    int* rowptr   = (int*)p;    p += (NN + 1) * sizeof(int);
    int* cursor   = (int*)p;    p += NN * sizeof(int);
    int* scsr     = (int*)p;    p += ET * sizeof(int);

    const int EB = (ET + 255) / 256;

    init0_kernel<<<256, 256, 0, stream>>>(counts, pooled);
    histcnt_kernel<<<EB, 256, 0, stream>>>(ei, counts, batch, cnt);
    scan_kernel<<<1, 1024, 0, stream>>>(counts, rowptr, cursor);
    fill_kernel<<<EB, 256, 0, stream>>>(ei, cursor, scsr);
    gemm1_kernel<<<NN / 8, 256, 0, stream>>>(x, W1, att_src1, att_dst1, h1, a_s1, a_d1);
    attn1_kernel<<<NN / 4, 256, 0, stream>>>(rowptr, scsr, (const float4*)a_s1,
                                             (const float4*)a_d1, (float4*)wcsr1,
                                             (float4*)invden1);
    emsg1_gather_kernel<<<NN / 2, 256, 0, stream>>>(rowptr, scsr, wcsr1, invden1,
                                                    (const __half2*)h1, (float2*)out1);
    gemm2_kernel<<<(NN + 31) / 32, 256, 0, stream>>>(out1, b1, W2, att_src2, att_dst2,
                                                     h2, a_s2, a_d2);
    attn2_kernel<<<NN / 4, 256, 0, stream>>>(rowptr, scsr, a_s2, a_d2, wcsr2, invden2);
    emsg2_gather_kernel<<<NN / 4, 256, 0, stream>>>(rowptr, scsr, wcsr2, invden2, h2, b2,
                                                    batch, pooled);
    final_kernel<<<GG, 64, 0, stream>>>(pooled, cnt, fc_w, fc_b, out);
}

// Round 5
// 472.302 us; speedup vs baseline: 3.2049x; 1.2420x over previous
//
#include <hip/hip_runtime.h>
#include <hip/hip_fp16.h>
#include <math.h>

#define NN 50000
#define FIN 128
#define HH 4
#define CC 64
#define HC (HH*CC)       // 256
#define GG 512
#define EE 800000
#define ET (EE + NN)     // 850000 edges incl. self-loops
#define NEG_SLOPE 0.2f
#define SCAN_NB 196      // ceil(NN/256)

__device__ __forceinline__ float waveReduceSum(float v) {
    #pragma unroll
    for (int off = 32; off > 0; off >>= 1) v += __shfl_xor(v, off);
    return v;
}

// zero counts / pooled / cnt (accumulated-into buffers; ws is not re-poisoned)
__global__ __launch_bounds__(256) void init0_kernel(int* __restrict__ counts,
                                                    float* __restrict__ pooled) {
    int i = blockIdx.x * 256 + threadIdx.x;
    int stride = gridDim.x * 256;
    for (int j = i; j < NN; j += stride) counts[j] = 0;
    for (int j = i; j < GG * CC + GG; j += stride) pooled[j] = 0.f;  // pooled then cnt contiguous
}

// histogram of dst + batch count, fused
__global__ __launch_bounds__(256) void histcnt_kernel(const int* __restrict__ ei,
                                                      int* __restrict__ counts,
                                                      const int* __restrict__ batch,
                                                      float* __restrict__ cnt) {
    int e = blockIdx.x * 256 + threadIdx.x;
    if (e < ET) {
        int d = (e < EE) ? ei[EE + e] : e - EE;
        atomicAdd(&counts[d], 1);
    }
    if (e < NN) atomicAdd(&cnt[batch[e]], 1.f);
}

// ---- three-phase device-wide exclusive scan of counts[NN] ----
// A: per-block (256 elems) reduce -> bsum[b]
__global__ __launch_bounds__(256) void scanA_kernel(const int* __restrict__ counts,
                                                    int* __restrict__ bsum) {
    __shared__ int sh[256];
    int t = threadIdx.x;
    int i = blockIdx.x * 256 + t;
    sh[t] = (i < NN) ? counts[i] : 0;
    __syncthreads();
    #pragma unroll
    for (int off = 128; off > 0; off >>= 1) {
        if (t < off) sh[t] += sh[t + off];
        __syncthreads();
    }
    if (t == 0) bsum[blockIdx.x] = sh[0];
}

// B: single small block: exclusive-scan bsum[SCAN_NB] in place
__global__ __launch_bounds__(256) void scanB_kernel(int* __restrict__ bsum) {
    __shared__ int sh[256];
    int t = threadIdx.x;
    int v = (t < SCAN_NB) ? bsum[t] : 0;
    sh[t] = v;
    __syncthreads();
    for (int off = 1; off < 256; off <<= 1) {
        int u = (t >= off) ? sh[t - off] : 0;
        __syncthreads();
        sh[t] += u;
        __syncthreads();
    }
    if (t < SCAN_NB) bsum[t] = sh[t] - v;   // exclusive
}

// C: per-block exclusive scan + block offset -> rowptr, cursor
__global__ __launch_bounds__(256) void scanC_kernel(const int* __restrict__ counts,
                                                    const int* __restrict__ bsum,
                                                    int* __restrict__ rowptr,
                                                    int* __restrict__ cursor) {
    __shared__ int sh[256];
    int t = threadIdx.x;
    int i = blockIdx.x * 256 + t;
    int v = (i < NN) ? counts[i] : 0;
    sh[t] = v;
    __syncthreads();
    for (int off = 1; off < 256; off <<= 1) {
        int u = (t >= off) ? sh[t - off] : 0;
        __syncthreads();
        sh[t] += u;
        __syncthreads();
    }
    int excl = sh[t] - v + bsum[blockIdx.x];
    if (i < NN) { rowptr[i] = excl; cursor[i] = excl; }
    if (i == NN - 1) rowptr[NN] = excl + v;   // = ET
}

__global__ __launch_bounds__(256) void fill_kernel(const int* __restrict__ ei,
                                                   int* __restrict__ cursor,
                                                   int* __restrict__ scsr) {
    int e = blockIdx.x * 256 + threadIdx.x;
    if (e >= ET) return;
    int s, d;
    if (e < EE) { s = ei[e]; d = ei[EE + e]; } else { s = d = e - EE; }
    int pos = atomicAdd(&cursor[d], 1);
    scsr[pos] = s;
}

// h1 = x @ W1  [N,256] (stored fp16); fused a_s1/a_d1 [N,4]. 8 nodes per block.
__global__ __launch_bounds__(256) void gemm1_kernel(
    const float* __restrict__ x, const float* __restrict__ W1,
    const float* __restrict__ att_src1, const float* __restrict__ att_dst1,
    __half* __restrict__ h1, float* __restrict__ a_s1, float* __restrict__ a_d1)
{
    __shared__ __align__(16) float xs[8][FIN];
    int n0 = blockIdx.x * 8;
    int t = threadIdx.x;
    for (int i = t; i < 8 * FIN; i += 256) {
        int r = i >> 7, k = i & 127;
        xs[r][k] = x[(size_t)(n0 + r) * FIN + k];   // grid exact: 50000 = 6250*8
    }
    __syncthreads();
    float acc[8];
    #pragma unroll
    for (int r = 0; r < 8; ++r) acc[r] = 0.f;
    for (int k = 0; k < FIN; k += 4) {
        float4 xv[8];
        #pragma unroll
        for (int r = 0; r < 8; ++r) xv[r] = *(const float4*)&xs[r][k];
        #pragma unroll
        for (int i = 0; i < 4; ++i) {
            float w = W1[(size_t)(k + i) * HC + t];
            #pragma unroll
            for (int r = 0; r < 8; ++r)
                acc[r] += ((const float*)&xv[r])[i] * w;
        }
    }
    int head = t >> 6, lane = t & 63;
    float asw = att_src1[head * CC + lane];
    float adw = att_dst1[head * CC + lane];
    #pragma unroll
    for (int r = 0; r < 8; ++r) {
        int n = n0 + r;
        h1[(size_t)n * HC + t] = __float2half(acc[r]);
        float vs = waveReduceSum(acc[r] * asw);
        float vd = waveReduceSum(acc[r] * adw);
        if (lane == 0) { a_s1[n * HH + head] = vs; a_d1[n * HH + head] = vd; }
    }
}

// per-dst edge-lane-parallel weights, layer 1. wave per dst, 4 dst/block.
// no max-subtraction: |alpha| ~ O(1), exp() safe; softmax shift-invariant.
__global__ __launch_bounds__(256) void attn1_kernel(
    const int* __restrict__ rowptr, const int* __restrict__ scsr,
    const float4* __restrict__ a_s4, const float4* __restrict__ a_d4,
    float4* __restrict__ wcsr4, float4* __restrict__ invden4)
{
    int d = blockIdx.x * 4 + (threadIdx.x >> 6);   // grid exact: 12500*4
    int lane = threadIdx.x & 63;
    int start = rowptr[d], end = rowptr[d + 1];
    float4 ad = a_d4[d];
    float den0 = 0.f, den1 = 0.f, den2 = 0.f, den3 = 0.f;
    for (int j = start + lane; j < end; j += 64) {
        float4 as = a_s4[scsr[j]];
        float a0 = as.x + ad.x, a1 = as.y + ad.y, a2 = as.z + ad.z, a3 = as.w + ad.w;
        a0 = (a0 > 0.f) ? a0 : NEG_SLOPE * a0;
        a1 = (a1 > 0.f) ? a1 : NEG_SLOPE * a1;
        a2 = (a2 > 0.f) ? a2 : NEG_SLOPE * a2;
        a3 = (a3 > 0.f) ? a3 : NEG_SLOPE * a3;
        float w0 = expf(a0), w1 = expf(a1), w2 = expf(a2), w3 = expf(a3);
        wcsr4[j] = make_float4(w0, w1, w2, w3);
        den0 += w0; den1 += w1; den2 += w2; den3 += w3;
    }
    den0 = waveReduceSum(den0);
    den1 = waveReduceSum(den1);
    den2 = waveReduceSum(den2);
    den3 = waveReduceSum(den3);
    if (lane == 0)
        invden4[d] = make_float4(1.f / (den0 + 1e-16f), 1.f / (den1 + 1e-16f),
                                 1.f / (den2 + 1e-16f), 1.f / (den3 + 1e-16f));
}

// pure gather-accumulate, layer 1: 2 dst per 256-thread block, half2 payload.
__global__ __launch_bounds__(256) void emsg1_gather_kernel(
    const int* __restrict__ rowptr, const int* __restrict__ scsr,
    const float* __restrict__ wcsr, const float* __restrict__ invden,
    const __half2* __restrict__ h1, float2* __restrict__ out1)
{
    int t = threadIdx.x;
    int g = t >> 7;            // which dst in block
    int u = t & 127;           // channel-pair index (2u, 2u+1)
    int d = blockIdx.x * 2 + g;   // grid exact: 25000*2
    int head = u >> 5;
    int start = rowptr[d], end = rowptr[d + 1];
    float ax = 0.f, ay = 0.f;
    int j = start;
    for (; j + 1 < end; j += 2) {
        int s0 = scsr[j], s1 = scsr[j + 1];
        float w0 = wcsr[j * 4 + head];
        float w1 = wcsr[(j + 1) * 4 + head];
        float2 v0 = __half22float2(h1[(size_t)s0 * 128 + u]);
        float2 v1 = __half22float2(h1[(size_t)s1 * 128 + u]);
        ax += w0 * v0.x + w1 * v1.x;
        ay += w0 * v0.y + w1 * v1.y;
    }
    if (j < end) {
        int s0 = scsr[j];
        float w0 = wcsr[j * 4 + head];
        float2 v0 = __half22float2(h1[(size_t)s0 * 128 + u]);
        ax += w0 * v0.x;
        ay += w0 * v0.y;
    }
    float inv = invden[d * 4 + head];
    out1[(size_t)d * 128 + u] = make_float2(ax * inv, ay * inv);
}

// h2 = relu(out1 + b1) @ W2  [N,64] f32; fused a_s2/a_d2. 32 nodes per block.
__global__ __launch_bounds__(256) void gemm2_kernel(
    const float* __restrict__ out1, const float* __restrict__ b1,
    const float* __restrict__ W2, const float* __restrict__ att_src2,
    const float* __restrict__ att_dst2,
    float* __restrict__ h2, float* __restrict__ a_s2, float* __restrict__ a_d2)
{
    __shared__ __align__(16) float xs[32][HC];
    int n0 = blockIdx.x * 32;
    int t = threadIdx.x;
    float bb = b1[t];
    for (int r = 0; r < 32; ++r) {
        int n = n0 + r;
        float v = (n < NN) ? out1[(size_t)n * HC + t] + bb : 0.f;
        xs[r][t] = v > 0.f ? v : 0.f;
    }
    __syncthreads();
    int wv = t >> 6, lane = t & 63;
    float acc[8];
    #pragma unroll
    for (int r = 0; r < 8; ++r) acc[r] = 0.f;
    for (int k = 0; k < HC; k += 4) {
        float4 xv[8];
        #pragma unroll
        for (int r = 0; r < 8; ++r) xv[r] = *(const float4*)&xs[wv * 8 + r][k];
        #pragma unroll
        for (int i = 0; i < 4; ++i) {
            float w = W2[(size_t)(k + i) * CC + lane];
            #pragma unroll
            for (int r = 0; r < 8; ++r)
                acc[r] += ((const float*)&xv[r])[i] * w;
        }
    }
    float asw = att_src2[lane], adw = att_dst2[lane];
    #pragma unroll
    for (int r = 0; r < 8; ++r) {
        int n = n0 + wv * 8 + r;
        float vs = waveReduceSum(acc[r] * asw);
        float vd = waveReduceSum(acc[r] * adw);
        if (n < NN) {
            h2[(size_t)n * CC + lane] = acc[r];
            if (lane == 0) { a_s2[n] = vs; a_d2[n] = vd; }
        }
    }
}

// per-dst edge-lane-parallel weights, layer 2 (1 head). wave per dst, 4/block.
__global__ __launch_bounds__(256) void attn2_kernel(
    const int* __restrict__ rowptr, const int* __restrict__ scsr,
    const float* __restrict__ a_s, const float* __restrict__ a_d,
    float* __restrict__ wcsr, float* __restrict__ invden)
{
    int d = blockIdx.x * 4 + (threadIdx.x >> 6);
    int lane = threadIdx.x & 63;
    int start = rowptr[d], end = rowptr[d + 1];
    float ad = a_d[d];
    float den = 0.f;
    for (int j = start + lane; j < end; j += 64) {
        float a = a_s[scsr[j]] + ad;
        a = (a > 0.f) ? a : NEG_SLOPE * a;
        float w = expf(a);
        wcsr[j] = w;
        den += w;
    }
    den = waveReduceSum(den);
    if (lane == 0) invden[d] = 1.f / (den + 1e-16f);
}

// pure gather layer 2 + fused relu/bias/mean-pool scatter. 1 wave/dst, 4/block.
__global__ __launch_bounds__(256) void emsg2_gather_kernel(
    const int* __restrict__ rowptr, const int* __restrict__ scsr,
    const float* __restrict__ wcsr, const float* __restrict__ invden,
    const float* __restrict__ h2, const float* __restrict__ b2,
    const int* __restrict__ batch, float* __restrict__ pooled)
{
    int d = blockIdx.x * 4 + (threadIdx.x >> 6);
    int lane = threadIdx.x & 63;
    int start = rowptr[d], end = rowptr[d + 1];
    float acc = 0.f;
    int j = start;
    for (; j + 1 < end; j += 2) {
        int s0 = scsr[j], s1 = scsr[j + 1];
        float w0 = wcsr[j], w1 = wcsr[j + 1];
        acc += w0 * h2[(size_t)s0 * CC + lane] + w1 * h2[(size_t)s1 * CC + lane];
    }
    if (j < end) acc += wcsr[j] * h2[(size_t)scsr[j] * CC + lane];
    float h = acc * invden[d] + b2[lane];
    h = h > 0.f ? h : 0.f;
    atomicAdd(&pooled[batch[d] * CC + lane], h);
}

__global__ void final_kernel(const float* __restrict__ pooled, const float* __restrict__ cnt,
    const float* __restrict__ fc_w, const float* __restrict__ fc_b, float* __restrict__ out)
{
    int g = blockIdx.x, lane = threadIdx.x;
    float v = pooled[g * CC + lane] / fmaxf(cnt[g], 1.f) * fc_w[lane];
    v = waveReduceSum(v);
    if (lane == 0) out[g] = v + fc_b[0];
}

extern "C" void kernel_launch(void* const* d_in, const int* in_sizes, int n_in,
                              void* d_out, int out_size, void* d_ws, size_t ws_size,
                              hipStream_t stream)
{
    const float* x        = (const float*)d_in[0];
    const float* W1       = (const float*)d_in[1];
    const float* att_src1 = (const float*)d_in[2];
    const float* att_dst1 = (const float*)d_in[3];
    const float* b1       = (const float*)d_in[4];
    const float* W2       = (const float*)d_in[5];
    const float* att_src2 = (const float*)d_in[6];
    const float* att_dst2 = (const float*)d_in[7];
    const float* b2       = (const float*)d_in[8];
    const float* fc_w     = (const float*)d_in[9];
    const float* fc_b     = (const float*)d_in[10];
    const int*   ei       = (const int*)d_in[11];   // [2, E] -> src = ei, dst = ei + EE
    const int*   batch    = (const int*)d_in[12];
    float* out = (float*)d_out;

    char* p = (char*)d_ws;
    __half* h1    = (__half*)p; p += (size_t)NN * HC * sizeof(__half);   // 25.6 MB
    float* out1   = (float*)p;  p += (size_t)NN * HC * sizeof(float);    // 51.2 MB
    float* h2     = (float*)p;  p += (size_t)NN * CC * sizeof(float);    // 12.8 MB
    float* wcsr1  = (float*)p;  p += (size_t)ET * HH * sizeof(float);    // 13.6 MB
    float* wcsr2  = (float*)p;  p += (size_t)ET * sizeof(float);         // 3.4 MB
    float* a_s1   = (float*)p;  p += (size_t)NN * HH * sizeof(float);
    float* a_d1   = (float*)p;  p += (size_t)NN * HH * sizeof(float);
    float* invden1= (float*)p;  p += (size_t)NN * HH * sizeof(float);
    float* a_s2   = (float*)p;  p += NN * sizeof(float);
    float* a_d2   = (float*)p;  p += NN * sizeof(float);
    float* invden2= (float*)p;  p += NN * sizeof(float);
    float* pooled = (float*)p;  p += (size_t)GG * CC * sizeof(float);    // pooled+cnt contiguous
    float* cnt    = (float*)p;  p += GG * sizeof(float);
    int* counts   = (int*)p;    p += NN * sizeof(int);
    int* rowptr   = (int*)p;    p += (NN + 1) * sizeof(int);
    int* cursor   = (int*)p;    p += NN * sizeof(int);
    int* scsr     = (int*)p;    p += ET * sizeof(int);
    int* bsum     = (int*)p;    p += SCAN_NB * sizeof(int);

    const int EB = (ET + 255) / 256;

    init0_kernel<<<256, 256, 0, stream>>>(counts, pooled);
    histcnt_kernel<<<EB, 256, 0, stream>>>(ei, counts, batch, cnt);
    scanA_kernel<<<SCAN_NB, 256, 0, stream>>>(counts, bsum);
    scanB_kernel<<<1, 256, 0, stream>>>(bsum);
    scanC_kernel<<<SCAN_NB, 256, 0, stream>>>(counts, bsum, rowptr, cursor);
    fill_kernel<<<EB, 256, 0, stream>>>(ei, cursor, scsr);
    gemm1_kernel<<<NN / 8, 256, 0, stream>>>(x, W1, att_src1, att_dst1, h1, a_s1, a_d1);
    attn1_kernel<<<NN / 4, 256, 0, stream>>>(rowptr, scsr, (const float4*)a_s1,
                                             (const float4*)a_d1, (float4*)wcsr1,
                                             (float4*)invden1);
    emsg1_gather_kernel<<<NN / 2, 256, 0, stream>>>(rowptr, scsr, wcsr1, invden1,
                                                    (const __half2*)h1, (float2*)out1);
    gemm2_kernel<<<(NN + 31) / 32, 256, 0, stream>>>(out1, b1, W2, att_src2, att_dst2,
                                                     h2, a_s2, a_d2);
    attn2_kernel<<<NN / 4, 256, 0, stream>>>(rowptr, scsr, a_s2, a_d2, wcsr2, invden2);
    emsg2_gather_kernel<<<NN / 4, 256, 0, stream>>>(rowptr, scsr, wcsr2, invden2, h2, b2,
                                                    batch, pooled);
    final_kernel<<<GG, 64, 0, stream>>>(pooled, cnt, fc_w, fc_b, out);
}

// Round 6
// 403.129 us; speedup vs baseline: 3.7548x; 1.1716x over previous
//
#include <hip/hip_runtime.h>
#include <hip/hip_fp16.h>
#include <math.h>

#define NN 50000
#define FIN 128
#define HH 4
#define CC 64
#define HC (HH*CC)       // 256
#define GG 512
#define EE 800000
#define ET (EE + NN)     // 850000 edges incl. self-loops
#define NEG_SLOPE 0.2f
#define SCAN_NB 196      // ceil(NN/256)

typedef _Float16 half8 __attribute__((ext_vector_type(8)));
typedef float floatx4 __attribute__((ext_vector_type(4)));

__device__ __forceinline__ float waveReduceSum(float v) {
    #pragma unroll
    for (int off = 32; off > 0; off >>= 1) v += __shfl_xor(v, off);
    return v;
}

// zero counts / pooled / cnt (accumulated-into buffers; ws is not re-poisoned)
__global__ __launch_bounds__(256) void init0_kernel(int* __restrict__ counts,
                                                    float* __restrict__ pooled) {
    int i = blockIdx.x * 256 + threadIdx.x;
    int stride = gridDim.x * 256;
    for (int j = i; j < NN; j += stride) counts[j] = 0;
    for (int j = i; j < GG * CC + GG; j += stride) pooled[j] = 0.f;  // pooled then cnt contiguous
}

// histogram of dst + batch count, fused
__global__ __launch_bounds__(256) void histcnt_kernel(const int* __restrict__ ei,
                                                      int* __restrict__ counts,
                                                      const int* __restrict__ batch,
                                                      float* __restrict__ cnt) {
    int e = blockIdx.x * 256 + threadIdx.x;
    if (e < ET) {
        int d = (e < EE) ? ei[EE + e] : e - EE;
        atomicAdd(&counts[d], 1);
    }
    if (e < NN) atomicAdd(&cnt[batch[e]], 1.f);
}

// W1t[n][k] = fp16(W1[k][n])  (256x128, 64 KB)
__global__ __launch_bounds__(256) void cvtw1_kernel(const float* __restrict__ W1,
                                                    __half* __restrict__ W1t) {
    int i = blockIdx.x * 256 + threadIdx.x;   // grid exact: 128*256 = 32768
    int n = i >> 7, k = i & 127;
    W1t[i] = __float2half(W1[(size_t)k * HC + n]);
}

// ---- three-phase device-wide exclusive scan of counts[NN] ----
__global__ __launch_bounds__(256) void scanA_kernel(const int* __restrict__ counts,
                                                    int* __restrict__ bsum) {
    __shared__ int sh[256];
    int t = threadIdx.x;
    int i = blockIdx.x * 256 + t;
    sh[t] = (i < NN) ? counts[i] : 0;
    __syncthreads();
    #pragma unroll
    for (int off = 128; off > 0; off >>= 1) {
        if (t < off) sh[t] += sh[t + off];
        __syncthreads();
    }
    if (t == 0) bsum[blockIdx.x] = sh[0];
}

__global__ __launch_bounds__(256) void scanB_kernel(int* __restrict__ bsum) {
    __shared__ int sh[256];
    int t = threadIdx.x;
    int v = (t < SCAN_NB) ? bsum[t] : 0;
    sh[t] = v;
    __syncthreads();
    for (int off = 1; off < 256; off <<= 1) {
        int u = (t >= off) ? sh[t - off] : 0;
        __syncthreads();
        sh[t] += u;
        __syncthreads();
    }
    if (t < SCAN_NB) bsum[t] = sh[t] - v;   // exclusive
}

__global__ __launch_bounds__(256) void scanC_kernel(const int* __restrict__ counts,
                                                    const int* __restrict__ bsum,
                                                    int* __restrict__ rowptr,
                                                    int* __restrict__ cursor) {
    __shared__ int sh[256];
    int t = threadIdx.x;
    int i = blockIdx.x * 256 + t;
    int v = (i < NN) ? counts[i] : 0;
    sh[t] = v;
    __syncthreads();
    for (int off = 1; off < 256; off <<= 1) {
        int u = (t >= off) ? sh[t - off] : 0;
        __syncthreads();
        sh[t] += u;
        __syncthreads();
    }
    int excl = sh[t] - v + bsum[blockIdx.x];
    if (i < NN) { rowptr[i] = excl; cursor[i] = excl; }
    if (i == NN - 1) rowptr[NN] = excl + v;   // = ET
}

__global__ __launch_bounds__(256) void fill_kernel(const int* __restrict__ ei,
                                                   int* __restrict__ cursor,
                                                   int* __restrict__ scsr) {
    int e = blockIdx.x * 256 + threadIdx.x;
    if (e >= ET) return;
    int s, d;
    if (e < EE) { s = ei[e]; d = ei[EE + e]; } else { s = d = e - EE; }
    int pos = atomicAdd(&cursor[d], 1);
    scsr[pos] = s;
}

// h1 = x @ W1 via fp16 MFMA (f32 accum); fused a_s1/a_d1.
// Block = 4 waves; each wave: 16-node tile x 128-col half.
// Fragment maps: A[m=l&15][k-slot], B[n=l&15][k-slot] (same slot order -> exact sum),
// D: col=l&15, row=(l>>4)*4+reg (verified layout).
__global__ __launch_bounds__(256) void gemm1_mfma_kernel(
    const float* __restrict__ x, const __half* __restrict__ W1t,
    const float* __restrict__ att_src1, const float* __restrict__ att_dst1,
    __half* __restrict__ h1, float* __restrict__ a_s1, float* __restrict__ a_d1)
{
    int w = threadIdx.x >> 6;                       // wave 0..3
    int l = threadIdx.x & 63;
    int nbase = blockIdx.x * 32 + (w >> 1) * 16;    // 16-node tile
    int chalf = (w & 1) * 128;                      // column half
    int lm = l & 15, lb = l >> 4;

    int m = nbase + lm; if (m >= NN) m = NN - 1;    // clamp tail loads
    half8 afrag[4];
    const float* xrow = x + (size_t)m * FIN + lb * 8;
    #pragma unroll
    for (int q = 0; q < 4; ++q) {
        floatx4 lo = *(const floatx4*)(xrow + q * 32);
        floatx4 hi = *(const floatx4*)(xrow + q * 32 + 4);
        half8 f;
        #pragma unroll
        for (int i = 0; i < 4; ++i) { f[i] = (_Float16)lo[i]; f[4 + i] = (_Float16)hi[i]; }
        afrag[q] = f;
    }
    floatx4 acc[8];
    #pragma unroll
    for (int t = 0; t < 8; ++t) acc[t] = (floatx4){0.f, 0.f, 0.f, 0.f};

    const __half* wt = W1t + (size_t)(chalf + lm) * FIN + lb * 8;
    #pragma unroll
    for (int t = 0; t < 8; ++t) {
        const __half* wtt = wt + (size_t)t * 16 * FIN;
        #pragma unroll
        for (int q = 0; q < 4; ++q) {
            half8 b = *(const half8*)(wtt + q * 32);
            acc[t] = __builtin_amdgcn_mfma_f32_16x16x32_f16(afrag[q], b, acc[t], 0, 0, 0);
        }
    }
    // epilogue: h1 store (fp16) + per-head attention dots
    #pragma unroll
    for (int hh = 0; hh < 2; ++hh) {
        float as_p[4] = {0.f, 0.f, 0.f, 0.f};
        float ad_p[4] = {0.f, 0.f, 0.f, 0.f};
        #pragma unroll
        for (int tt = 0; tt < 4; ++tt) {
            int t = hh * 4 + tt;
            int col = chalf + t * 16 + lm;
            float asw = att_src1[col], adw = att_dst1[col];
            #pragma unroll
            for (int r = 0; r < 4; ++r) {
                int n = nbase + lb * 4 + r;
                float v = acc[t][r];
                if (n < NN) h1[(size_t)n * HC + col] = __float2half(v);
                as_p[r] += v * asw;
                ad_p[r] += v * adw;
            }
        }
        #pragma unroll
        for (int off = 1; off < 16; off <<= 1) {
            #pragma unroll
            for (int r = 0; r < 4; ++r) {
                as_p[r] += __shfl_xor(as_p[r], off);
                ad_p[r] += __shfl_xor(ad_p[r], off);
            }
        }
        if (lm == 0) {
            int head = (chalf >> 6) + hh;
            #pragma unroll
            for (int r = 0; r < 4; ++r) {
                int n = nbase + lb * 4 + r;
                if (n < NN) { a_s1[n * HH + head] = as_p[r]; a_d1[n * HH + head] = ad_p[r]; }
            }
        }
    }
}

// per-dst edge-lane-parallel weights, layer 1. wave per dst, 4 dst/block.
__global__ __launch_bounds__(256) void attn1_kernel(
    const int* __restrict__ rowptr, const int* __restrict__ scsr,
    const float4* __restrict__ a_s4, const float4* __restrict__ a_d4,
    float4* __restrict__ wcsr4, float4* __restrict__ invden4)
{
    int d = blockIdx.x * 4 + (threadIdx.x >> 6);   // grid exact: 12500*4
    int lane = threadIdx.x & 63;
    int start = rowptr[d], end = rowptr[d + 1];
    float4 ad = a_d4[d];
    float den0 = 0.f, den1 = 0.f, den2 = 0.f, den3 = 0.f;
    for (int j = start + lane; j < end; j += 64) {
        float4 as = a_s4[scsr[j]];
        float a0 = as.x + ad.x, a1 = as.y + ad.y, a2 = as.z + ad.z, a3 = as.w + ad.w;
        a0 = (a0 > 0.f) ? a0 : NEG_SLOPE * a0;
        a1 = (a1 > 0.f) ? a1 : NEG_SLOPE * a1;
        a2 = (a2 > 0.f) ? a2 : NEG_SLOPE * a2;
        a3 = (a3 > 0.f) ? a3 : NEG_SLOPE * a3;
        float w0 = expf(a0), w1 = expf(a1), w2 = expf(a2), w3 = expf(a3);
        wcsr4[j] = make_float4(w0, w1, w2, w3);
        den0 += w0; den1 += w1; den2 += w2; den3 += w3;
    }
    den0 = waveReduceSum(den0);
    den1 = waveReduceSum(den1);
    den2 = waveReduceSum(den2);
    den3 = waveReduceSum(den3);
    if (lane == 0)
        invden4[d] = make_float4(1.f / (den0 + 1e-16f), 1.f / (den1 + 1e-16f),
                                 1.f / (den2 + 1e-16f), 1.f / (den3 + 1e-16f));
}

// pure gather-accumulate, layer 1: 2 dst per 256-thread block, half2 payload, x4 unroll.
__global__ __launch_bounds__(256) void emsg1_gather_kernel(
    const int* __restrict__ rowptr, const int* __restrict__ scsr,
    const float* __restrict__ wcsr, const float* __restrict__ invden,
    const __half2* __restrict__ h1, float2* __restrict__ out1)
{
    int t = threadIdx.x;
    int g = t >> 7;            // which dst in block
    int u = t & 127;           // channel-pair index (2u, 2u+1)
    int d = blockIdx.x * 2 + g;   // grid exact: 25000*2
    int head = u >> 5;
    int start = rowptr[d], end = rowptr[d + 1];
    float ax = 0.f, ay = 0.f;
    int j = start;
    for (; j + 3 < end; j += 4) {
        int s0 = scsr[j], s1 = scsr[j + 1], s2 = scsr[j + 2], s3 = scsr[j + 3];
        float w0 = wcsr[j * 4 + head];
        float w1 = wcsr[(j + 1) * 4 + head];
        float w2 = wcsr[(j + 2) * 4 + head];
        float w3 = wcsr[(j + 3) * 4 + head];
        float2 v0 = __half22float2(h1[(size_t)s0 * 128 + u]);
        float2 v1 = __half22float2(h1[(size_t)s1 * 128 + u]);
        float2 v2 = __half22float2(h1[(size_t)s2 * 128 + u]);
        float2 v3 = __half22float2(h1[(size_t)s3 * 128 + u]);
        ax += w0 * v0.x + w1 * v1.x + w2 * v2.x + w3 * v3.x;
        ay += w0 * v0.y + w1 * v1.y + w2 * v2.y + w3 * v3.y;
    }
    for (; j < end; ++j) {
        int s0 = scsr[j];
        float w0 = wcsr[j * 4 + head];
        float2 v0 = __half22float2(h1[(size_t)s0 * 128 + u]);
        ax += w0 * v0.x;
        ay += w0 * v0.y;
    }
    float inv = invden[d * 4 + head];
    out1[(size_t)d * 128 + u] = make_float2(ax * inv, ay * inv);
}

// h2 = relu(out1 + b1) @ W2  [N,64] f32; fused a_s2/a_d2. 32 nodes per block.
__global__ __launch_bounds__(256) void gemm2_kernel(
    const float* __restrict__ out1, const float* __restrict__ b1,
    const float* __restrict__ W2, const float* __restrict__ att_src2,
    const float* __restrict__ att_dst2,
    float* __restrict__ h2, float* __restrict__ a_s2, float* __restrict__ a_d2)
{
    __shared__ __align__(16) float xs[32][HC];
    int n0 = blockIdx.x * 32;
    int t = threadIdx.x;
    float bb = b1[t];
    for (int r = 0; r < 32; ++r) {
        int n = n0 + r;
        float v = (n < NN) ? out1[(size_t)n * HC + t] + bb : 0.f;
        xs[r][t] = v > 0.f ? v : 0.f;
    }
    __syncthreads();
    int wv = t >> 6, lane = t & 63;
    float acc[8];
    #pragma unroll
    for (int r = 0; r < 8; ++r) acc[r] = 0.f;
    for (int k = 0; k < HC; k += 4) {
        float4 xv[8];
        #pragma unroll
        for (int r = 0; r < 8; ++r) xv[r] = *(const float4*)&xs[wv * 8 + r][k];
        #pragma unroll
        for (int i = 0; i < 4; ++i) {
            float w = W2[(size_t)(k + i) * CC + lane];
            #pragma unroll
            for (int r = 0; r < 8; ++r)
                acc[r] += ((const float*)&xv[r])[i] * w;
        }
    }
    float asw = att_src2[lane], adw = att_dst2[lane];
    #pragma unroll
    for (int r = 0; r < 8; ++r) {
        int n = n0 + wv * 8 + r;
        float vs = waveReduceSum(acc[r] * asw);
        float vd = waveReduceSum(acc[r] * adw);
        if (n < NN) {
            h2[(size_t)n * CC + lane] = acc[r];
            if (lane == 0) { a_s2[n] = vs; a_d2[n] = vd; }
        }
    }
}

// per-dst edge-lane-parallel weights, layer 2 (1 head). wave per dst, 4/block.
__global__ __launch_bounds__(256) void attn2_kernel(
    const int* __restrict__ rowptr, const int* __restrict__ scsr,
    const float* __restrict__ a_s, const float* __restrict__ a_d,
    float* __restrict__ wcsr, float* __restrict__ invden)
{
    int d = blockIdx.x * 4 + (threadIdx.x >> 6);
    int lane = threadIdx.x & 63;
    int start = rowptr[d], end = rowptr[d + 1];
    float ad = a_d[d];
    float den = 0.f;
    for (int j = start + lane; j < end; j += 64) {
        float a = a_s[scsr[j]] + ad;
        a = (a > 0.f) ? a : NEG_SLOPE * a;
        float w = expf(a);
        wcsr[j] = w;
        den += w;
    }
    den = waveReduceSum(den);
    if (lane == 0) invden[d] = 1.f / (den + 1e-16f);
}

// pure gather layer 2 + fused relu/bias/mean-pool scatter. 1 wave/dst, 4/block.
__global__ __launch_bounds__(256) void emsg2_gather_kernel(
    const int* __restrict__ rowptr, const int* __restrict__ scsr,
    const float* __restrict__ wcsr, const float* __restrict__ invden,
    const float* __restrict__ h2, const float* __restrict__ b2,
    const int* __restrict__ batch, float* __restrict__ pooled)
{
    int d = blockIdx.x * 4 + (threadIdx.x >> 6);
    int lane = threadIdx.x & 63;
    int start = rowptr[d], end = rowptr[d + 1];
    float acc = 0.f;
    int j = start;
    for (; j + 1 < end; j += 2) {
        int s0 = scsr[j], s1 = scsr[j + 1];
        float w0 = wcsr[j], w1 = wcsr[j + 1];
        acc += w0 * h2[(size_t)s0 * CC + lane] + w1 * h2[(size_t)s1 * CC + lane];
    }
    if (j < end) acc += wcsr[j] * h2[(size_t)scsr[j] * CC + lane];
    float h = acc * invden[d] + b2[lane];
    h = h > 0.f ? h : 0.f;
    atomicAdd(&pooled[batch[d] * CC + lane], h);
}

__global__ void final_kernel(const float* __restrict__ pooled, const float* __restrict__ cnt,
    const float* __restrict__ fc_w, const float* __restrict__ fc_b, float* __restrict__ out)
{
    int g = blockIdx.x, lane = threadIdx.x;
    float v = pooled[g * CC + lane] / fmaxf(cnt[g], 1.f) * fc_w[lane];
    v = waveReduceSum(v);
    if (lane == 0) out[g] = v + fc_b[0];
}

extern "C" void kernel_launch(void* const* d_in, const int* in_sizes, int n_in,
                              void* d_out, int out_size, void* d_ws, size_t ws_size,
                              hipStream_t stream)
{
    const float* x        = (const float*)d_in[0];
    const float* W1       = (const float*)d_in[1];
    const float* att_src1 = (const float*)d_in[2];
    const float* att_dst1 = (const float*)d_in[3];
    const float* b1       = (const float*)d_in[4];
    const float* W2       = (const float*)d_in[5];
    const float* att_src2 = (const float*)d_in[6];
    const float* att_dst2 = (const float*)d_in[7];
    const float* b2       = (const float*)d_in[8];
    const float* fc_w     = (const float*)d_in[9];
    const float* fc_b     = (const float*)d_in[10];
    const int*   ei       = (const int*)d_in[11];   // [2, E] -> src = ei, dst = ei + EE
    const int*   batch    = (const int*)d_in[12];
    float* out = (float*)d_out;

    char* p = (char*)d_ws;
    __half* W1t   = (__half*)p; p += (size_t)HC * FIN * sizeof(__half);  // 64 KB (16B-aligned)
    __half* h1    = (__half*)p; p += (size_t)NN * HC * sizeof(__half);   // 25.6 MB
    float* out1   = (float*)p;  p += (size_t)NN * HC * sizeof(float);    // 51.2 MB
    float* h2     = (float*)p;  p += (size_t)NN * CC * sizeof(float);    // 12.8 MB
    float* wcsr1  = (float*)p;  p += (size_t)ET * HH * sizeof(float);    // 13.6 MB
    float* wcsr2  = (float*)p;  p += (size_t)ET * sizeof(float);         // 3.4 MB
    float* a_s1   = (float*)p;  p += (size_t)NN * HH * sizeof(float);
    float* a_d1   = (float*)p;  p += (size_t)NN * HH * sizeof(float);
    float* invden1= (float*)p;  p += (size_t)NN * HH * sizeof(float);
    float* a_s2   = (float*)p;  p += NN * sizeof(float);
    float* a_d2   = (float*)p;  p += NN * sizeof(float);
    float* invden2= (float*)p;  p += NN * sizeof(float);
    float* pooled = (float*)p;  p += (size_t)GG * CC * sizeof(float);    // pooled+cnt contiguous
    float* cnt    = (float*)p;  p += GG * sizeof(float);
    int* counts   = (int*)p;    p += NN * sizeof(int);
    int* rowptr   = (int*)p;    p += (NN + 1) * sizeof(int);
    int* cursor   = (int*)p;    p += NN * sizeof(int);
    int* scsr     = (int*)p;    p += ET * sizeof(int);
    int* bsum     = (int*)p;    p += SCAN_NB * sizeof(int);

    const int EB = (ET + 255) / 256;

    init0_kernel<<<256, 256, 0, stream>>>(counts, pooled);
    histcnt_kernel<<<EB, 256, 0, stream>>>(ei, counts, batch, cnt);
    cvtw1_kernel<<<(HC * FIN) / 256, 256, 0, stream>>>(W1, W1t);
    scanA_kernel<<<SCAN_NB, 256, 0, stream>>>(counts, bsum);
    scanB_kernel<<<1, 256, 0, stream>>>(bsum);
    scanC_kernel<<<SCAN_NB, 256, 0, stream>>>(counts, bsum, rowptr, cursor);
    fill_kernel<<<EB, 256, 0, stream>>>(ei, cursor, scsr);
    gemm1_mfma_kernel<<<(NN + 31) / 32, 256, 0, stream>>>(x, W1t, att_src1, att_dst1,
                                                          h1, a_s1, a_d1);
    attn1_kernel<<<NN / 4, 256, 0, stream>>>(rowptr, scsr, (const float4*)a_s1,
                                             (const float4*)a_d1, (float4*)wcsr1,
                                             (float4*)invden1);
    emsg1_gather_kernel<<<NN / 2, 256, 0, stream>>>(rowptr, scsr, wcsr1, invden1,
                                                    (const __half2*)h1, (float2*)out1);
    gemm2_kernel<<<(NN + 31) / 32, 256, 0, stream>>>(out1, b1, W2, att_src2, att_dst2,
                                                     h2, a_s2, a_d2);
    attn2_kernel<<<NN / 4, 256, 0, stream>>>(rowptr, scsr, a_s2, a_d2, wcsr2, invden2);
    emsg2_gather_kernel<<<NN / 4, 256, 0, stream>>>(rowptr, scsr, wcsr2, invden2, h2, b2,
                                                    batch, pooled);
    final_kernel<<<GG, 64, 0, stream>>>(pooled, cnt, fc_w, fc_b, out);
}

// Round 7
// 392.985 us; speedup vs baseline: 3.8518x; 1.0258x over previous
//
#include <hip/hip_runtime.h>
#include <hip/hip_fp16.h>
#include <math.h>

#define NN 50000
#define FIN 128
#define HH 4
#define CC 64
#define HC (HH*CC)       // 256
#define GG 512
#define EE 800000
#define ET (EE + NN)     // 850000 edges incl. self-loops
#define NEG_SLOPE 0.2f
#define SCAN_NB 196      // ceil(NN/256)

typedef _Float16 half8 __attribute__((ext_vector_type(8)));
typedef float floatx4 __attribute__((ext_vector_type(4)));

__device__ __forceinline__ float waveReduceSum(float v) {
    #pragma unroll
    for (int off = 32; off > 0; off >>= 1) v += __shfl_xor(v, off);
    return v;
}

// zero counts / pooled / cnt (accumulated-into buffers; ws is not re-poisoned)
__global__ __launch_bounds__(256) void init0_kernel(int* __restrict__ counts,
                                                    float* __restrict__ pooled) {
    int i = blockIdx.x * 256 + threadIdx.x;
    int stride = gridDim.x * 256;
    for (int j = i; j < NN; j += stride) counts[j] = 0;
    for (int j = i; j < GG * CC + GG; j += stride) pooled[j] = 0.f;  // pooled then cnt contiguous
}

// histogram of dst + batch count, fused
__global__ __launch_bounds__(256) void histcnt_kernel(const int* __restrict__ ei,
                                                      int* __restrict__ counts,
                                                      const int* __restrict__ batch,
                                                      float* __restrict__ cnt) {
    int e = blockIdx.x * 256 + threadIdx.x;
    if (e < ET) {
        int d = (e < EE) ? ei[EE + e] : e - EE;
        atomicAdd(&counts[d], 1);
    }
    if (e < NN) atomicAdd(&cnt[batch[e]], 1.f);
}

// W1t[n][k] = fp16(W1[k][n]) (256x128) ; W2t[n][k] = fp16(W2[k][n]) (64x256)
__global__ __launch_bounds__(256) void cvtw_kernel(const float* __restrict__ W1,
                                                   const float* __restrict__ W2,
                                                   __half* __restrict__ W1t,
                                                   __half* __restrict__ W2t) {
    int i = blockIdx.x * 256 + threadIdx.x;   // grid exact: 192*256 = 49152
    if (i < HC * FIN) {
        int n = i >> 7, k = i & 127;
        W1t[i] = __float2half(W1[(size_t)k * HC + n]);
    } else {
        int i2 = i - HC * FIN;                // 0..16383
        int n = i2 >> 8, k = i2 & 255;
        W2t[i2] = __float2half(W2[(size_t)k * CC + n]);
    }
}

// ---- three-phase device-wide exclusive scan of counts[NN] ----
__global__ __launch_bounds__(256) void scanA_kernel(const int* __restrict__ counts,
                                                    int* __restrict__ bsum) {
    __shared__ int sh[256];
    int t = threadIdx.x;
    int i = blockIdx.x * 256 + t;
    sh[t] = (i < NN) ? counts[i] : 0;
    __syncthreads();
    #pragma unroll
    for (int off = 128; off > 0; off >>= 1) {
        if (t < off) sh[t] += sh[t + off];
        __syncthreads();
    }
    if (t == 0) bsum[blockIdx.x] = sh[0];
}

__global__ __launch_bounds__(256) void scanB_kernel(int* __restrict__ bsum) {
    __shared__ int sh[256];
    int t = threadIdx.x;
    int v = (t < SCAN_NB) ? bsum[t] : 0;
    sh[t] = v;
    __syncthreads();
    for (int off = 1; off < 256; off <<= 1) {
        int u = (t >= off) ? sh[t - off] : 0;
        __syncthreads();
        sh[t] += u;
        __syncthreads();
    }
    if (t < SCAN_NB) bsum[t] = sh[t] - v;   // exclusive
}

__global__ __launch_bounds__(256) void scanC_kernel(const int* __restrict__ counts,
                                                    const int* __restrict__ bsum,
                                                    int* __restrict__ rowptr,
                                                    int* __restrict__ cursor) {
    __shared__ int sh[256];
    int t = threadIdx.x;
    int i = blockIdx.x * 256 + t;
    int v = (i < NN) ? counts[i] : 0;
    sh[t] = v;
    __syncthreads();
    for (int off = 1; off < 256; off <<= 1) {
        int u = (t >= off) ? sh[t - off] : 0;
        __syncthreads();
        sh[t] += u;
        __syncthreads();
    }
    int excl = sh[t] - v + bsum[blockIdx.x];
    if (i < NN) { rowptr[i] = excl; cursor[i] = excl; }
    if (i == NN - 1) rowptr[NN] = excl + v;   // = ET
}

__global__ __launch_bounds__(256) void fill_kernel(const int* __restrict__ ei,
                                                   int* __restrict__ cursor,
                                                   int* __restrict__ scsr) {
    int e = blockIdx.x * 256 + threadIdx.x;
    if (e >= ET) return;
    int s, d;
    if (e < EE) { s = ei[e]; d = ei[EE + e]; } else { s = d = e - EE; }
    int pos = atomicAdd(&cursor[d], 1);
    scsr[pos] = s;
}

// h1 = x @ W1 via fp16 MFMA (f32 accum); fused a_s1/a_d1.
__global__ __launch_bounds__(256) void gemm1_mfma_kernel(
    const float* __restrict__ x, const __half* __restrict__ W1t,
    const float* __restrict__ att_src1, const float* __restrict__ att_dst1,
    __half* __restrict__ h1, float* __restrict__ a_s1, float* __restrict__ a_d1)
{
    int w = threadIdx.x >> 6;                       // wave 0..3
    int l = threadIdx.x & 63;
    int nbase = blockIdx.x * 32 + (w >> 1) * 16;    // 16-node tile
    int chalf = (w & 1) * 128;                      // column half
    int lm = l & 15, lb = l >> 4;

    int m = nbase + lm; if (m >= NN) m = NN - 1;    // clamp tail loads
    half8 afrag[4];
    const float* xrow = x + (size_t)m * FIN + lb * 8;
    #pragma unroll
    for (int q = 0; q < 4; ++q) {
        floatx4 lo = *(const floatx4*)(xrow + q * 32);
        floatx4 hi = *(const floatx4*)(xrow + q * 32 + 4);
        half8 f;
        #pragma unroll
        for (int i = 0; i < 4; ++i) { f[i] = (_Float16)lo[i]; f[4 + i] = (_Float16)hi[i]; }
        afrag[q] = f;
    }
    floatx4 acc[8];
    #pragma unroll
    for (int t = 0; t < 8; ++t) acc[t] = (floatx4){0.f, 0.f, 0.f, 0.f};

    const __half* wt = W1t + (size_t)(chalf + lm) * FIN + lb * 8;
    #pragma unroll
    for (int t = 0; t < 8; ++t) {
        const __half* wtt = wt + (size_t)t * 16 * FIN;
        #pragma unroll
        for (int q = 0; q < 4; ++q) {
            half8 b = *(const half8*)(wtt + q * 32);
            acc[t] = __builtin_amdgcn_mfma_f32_16x16x32_f16(afrag[q], b, acc[t], 0, 0, 0);
        }
    }
    #pragma unroll
    for (int hh = 0; hh < 2; ++hh) {
        float as_p[4] = {0.f, 0.f, 0.f, 0.f};
        float ad_p[4] = {0.f, 0.f, 0.f, 0.f};
        #pragma unroll
        for (int tt = 0; tt < 4; ++tt) {
            int t = hh * 4 + tt;
            int col = chalf + t * 16 + lm;
            float asw = att_src1[col], adw = att_dst1[col];
            #pragma unroll
            for (int r = 0; r < 4; ++r) {
                int n = nbase + lb * 4 + r;
                float v = acc[t][r];
                if (n < NN) h1[(size_t)n * HC + col] = __float2half(v);
                as_p[r] += v * asw;
                ad_p[r] += v * adw;
            }
        }
        #pragma unroll
        for (int off = 1; off < 16; off <<= 1) {
            #pragma unroll
            for (int r = 0; r < 4; ++r) {
                as_p[r] += __shfl_xor(as_p[r], off);
                ad_p[r] += __shfl_xor(ad_p[r], off);
            }
        }
        if (lm == 0) {
            int head = (chalf >> 6) + hh;
            #pragma unroll
            for (int r = 0; r < 4; ++r) {
                int n = nbase + lb * 4 + r;
                if (n < NN) { a_s1[n * HH + head] = as_p[r]; a_d1[n * HH + head] = ad_p[r]; }
            }
        }
    }
}

// per-dst edge-lane-parallel weights, layer 1. wave per dst, 4 dst/block.
__global__ __launch_bounds__(256) void attn1_kernel(
    const int* __restrict__ rowptr, const int* __restrict__ scsr,
    const float4* __restrict__ a_s4, const float4* __restrict__ a_d4,
    float4* __restrict__ wcsr4, float4* __restrict__ invden4)
{
    int d = blockIdx.x * 4 + (threadIdx.x >> 6);   // grid exact: 12500*4
    int lane = threadIdx.x & 63;
    int start = rowptr[d], end = rowptr[d + 1];
    float4 ad = a_d4[d];
    float den0 = 0.f, den1 = 0.f, den2 = 0.f, den3 = 0.f;
    for (int j = start + lane; j < end; j += 64) {
        float4 as = a_s4[__builtin_nontemporal_load(&scsr[j])];
        float a0 = as.x + ad.x, a1 = as.y + ad.y, a2 = as.z + ad.z, a3 = as.w + ad.w;
        a0 = (a0 > 0.f) ? a0 : NEG_SLOPE * a0;
        a1 = (a1 > 0.f) ? a1 : NEG_SLOPE * a1;
        a2 = (a2 > 0.f) ? a2 : NEG_SLOPE * a2;
        a3 = (a3 > 0.f) ? a3 : NEG_SLOPE * a3;
        float w0 = expf(a0), w1 = expf(a1), w2 = expf(a2), w3 = expf(a3);
        wcsr4[j] = make_float4(w0, w1, w2, w3);
        den0 += w0; den1 += w1; den2 += w2; den3 += w3;
    }
    den0 = waveReduceSum(den0);
    den1 = waveReduceSum(den1);
    den2 = waveReduceSum(den2);
    den3 = waveReduceSum(den3);
    if (lane == 0)
        invden4[d] = make_float4(1.f / (den0 + 1e-16f), 1.f / (den1 + 1e-16f),
                                 1.f / (den2 + 1e-16f), 1.f / (den3 + 1e-16f));
}

// gather-accumulate layer 1 + fused bias1/relu, fp16 out. 2 dst per 256-thread block.
__global__ __launch_bounds__(256) void emsg1_gather_kernel(
    const int* __restrict__ rowptr, const int* __restrict__ scsr,
    const float* __restrict__ wcsr, const float* __restrict__ invden,
    const __half2* __restrict__ h1, const float2* __restrict__ b1_2,
    __half2* __restrict__ out1r)
{
    int t = threadIdx.x;
    int g = t >> 7;            // which dst in block
    int u = t & 127;           // channel-pair index (2u, 2u+1)
    int d = blockIdx.x * 2 + g;   // grid exact: 25000*2
    int head = u >> 5;
    int start = rowptr[d], end = rowptr[d + 1];
    float ax = 0.f, ay = 0.f;
    int j = start;
    for (; j + 3 < end; j += 4) {
        int s0 = __builtin_nontemporal_load(&scsr[j]);
        int s1 = __builtin_nontemporal_load(&scsr[j + 1]);
        int s2 = __builtin_nontemporal_load(&scsr[j + 2]);
        int s3 = __builtin_nontemporal_load(&scsr[j + 3]);
        float w0 = __builtin_nontemporal_load(&wcsr[j * 4 + head]);
        float w1 = __builtin_nontemporal_load(&wcsr[(j + 1) * 4 + head]);
        float w2 = __builtin_nontemporal_load(&wcsr[(j + 2) * 4 + head]);
        float w3 = __builtin_nontemporal_load(&wcsr[(j + 3) * 4 + head]);
        float2 v0 = __half22float2(h1[(size_t)s0 * 128 + u]);
        float2 v1 = __half22float2(h1[(size_t)s1 * 128 + u]);
        float2 v2 = __half22float2(h1[(size_t)s2 * 128 + u]);
        float2 v3 = __half22float2(h1[(size_t)s3 * 128 + u]);
        ax += w0 * v0.x + w1 * v1.x + w2 * v2.x + w3 * v3.x;
        ay += w0 * v0.y + w1 * v1.y + w2 * v2.y + w3 * v3.y;
    }
    for (; j < end; ++j) {
        int s0 = __builtin_nontemporal_load(&scsr[j]);
        float w0 = __builtin_nontemporal_load(&wcsr[j * 4 + head]);
        float2 v0 = __half22float2(h1[(size_t)s0 * 128 + u]);
        ax += w0 * v0.x;
        ay += w0 * v0.y;
    }
    float inv = invden[d * 4 + head];
    float2 bb = b1_2[u];
    float rx = ax * inv + bb.x; rx = rx > 0.f ? rx : 0.f;
    float ry = ay * inv + bb.y; ry = ry > 0.f ? ry : 0.f;
    out1r[(size_t)d * 128 + u] = __floats2half2_rn(rx, ry);
}

// h2 = out1r @ W2 via fp16 MFMA; fused a_s2/a_d2. 64 nodes/block, 4 waves.
__global__ __launch_bounds__(256) void gemm2_mfma_kernel(
    const __half* __restrict__ out1r, const __half* __restrict__ W2t,
    const float* __restrict__ att_src2, const float* __restrict__ att_dst2,
    __half* __restrict__ h2, float* __restrict__ a_s2, float* __restrict__ a_d2)
{
    int w = threadIdx.x >> 6;
    int l = threadIdx.x & 63;
    int nbase = blockIdx.x * 64 + w * 16;
    int lm = l & 15, lb = l >> 4;

    int m = nbase + lm; if (m >= NN) m = NN - 1;
    half8 afrag[8];
    const __half* arow = out1r + (size_t)m * HC + lb * 8;
    #pragma unroll
    for (int q = 0; q < 8; ++q) afrag[q] = *(const half8*)(arow + q * 32);

    floatx4 acc[4];
    #pragma unroll
    for (int t = 0; t < 4; ++t) acc[t] = (floatx4){0.f, 0.f, 0.f, 0.f};

    const __half* wt = W2t + (size_t)lm * HC + lb * 8;
    #pragma unroll
    for (int t = 0; t < 4; ++t) {
        const __half* wtt = wt + (size_t)t * 16 * HC;
        #pragma unroll
        for (int q = 0; q < 8; ++q) {
            half8 b = *(const half8*)(wtt + q * 32);
            acc[t] = __builtin_amdgcn_mfma_f32_16x16x32_f16(afrag[q], b, acc[t], 0, 0, 0);
        }
    }
    float as_p[4] = {0.f, 0.f, 0.f, 0.f};
    float ad_p[4] = {0.f, 0.f, 0.f, 0.f};
    #pragma unroll
    for (int t = 0; t < 4; ++t) {
        int col = t * 16 + lm;
        float asw = att_src2[col], adw = att_dst2[col];
        #pragma unroll
        for (int r = 0; r < 4; ++r) {
            int n = nbase + lb * 4 + r;
            float v = acc[t][r];
            if (n < NN) h2[(size_t)n * CC + col] = __float2half(v);
            as_p[r] += v * asw;
            ad_p[r] += v * adw;
        }
    }
    #pragma unroll
    for (int off = 1; off < 16; off <<= 1) {
        #pragma unroll
        for (int r = 0; r < 4; ++r) {
            as_p[r] += __shfl_xor(as_p[r], off);
            ad_p[r] += __shfl_xor(ad_p[r], off);
        }
    }
    if (lm == 0) {
        #pragma unroll
        for (int r = 0; r < 4; ++r) {
            int n = nbase + lb * 4 + r;
            if (n < NN) { a_s2[n] = as_p[r]; a_d2[n] = ad_p[r]; }
        }
    }
}

// per-dst edge-lane-parallel weights, layer 2 (1 head). wave per dst, 4/block.
__global__ __launch_bounds__(256) void attn2_kernel(
    const int* __restrict__ rowptr, const int* __restrict__ scsr,
    const float* __restrict__ a_s, const float* __restrict__ a_d,
    float* __restrict__ wcsr, float* __restrict__ invden)
{
    int d = blockIdx.x * 4 + (threadIdx.x >> 6);
    int lane = threadIdx.x & 63;
    int start = rowptr[d], end = rowptr[d + 1];
    float ad = a_d[d];
    float den = 0.f;
    for (int j = start + lane; j < end; j += 64) {
        float a = a_s[__builtin_nontemporal_load(&scsr[j])] + ad;
        a = (a > 0.f) ? a : NEG_SLOPE * a;
        float w = expf(a);
        wcsr[j] = w;
        den += w;
    }
    den = waveReduceSum(den);
    if (lane == 0) invden[d] = 1.f / (den + 1e-16f);
}

// gather layer 2 (fp16 h2) + fused relu/bias/mean-pool scatter.
// 1 wave/dst, 4/block; lanes: u=ch-pair (0..31), eh=edge parity.
__global__ __launch_bounds__(256) void emsg2_gather_kernel(
    const int* __restrict__ rowptr, const int* __restrict__ scsr,
    const float* __restrict__ wcsr, const float* __restrict__ invden,
    const __half2* __restrict__ h2, const float2* __restrict__ b2_2,
    const int* __restrict__ batch, float* __restrict__ pooled)
{
    int d = blockIdx.x * 4 + (threadIdx.x >> 6);
    int lane = threadIdx.x & 63;
    int u = lane & 31;
    int eh = lane >> 5;
    int start = rowptr[d], end = rowptr[d + 1];
    float ax = 0.f, ay = 0.f;
    int j = start + eh;
    for (; j + 2 < end; j += 4) {
        int s0 = __builtin_nontemporal_load(&scsr[j]);
        int s1 = __builtin_nontemporal_load(&scsr[j + 2]);
        float w0 = __builtin_nontemporal_load(&wcsr[j]);
        float w1 = __builtin_nontemporal_load(&wcsr[j + 2]);
        float2 v0 = __half22float2(h2[(size_t)s0 * 32 + u]);
        float2 v1 = __half22float2(h2[(size_t)s1 * 32 + u]);
        ax += w0 * v0.x + w1 * v1.x;
        ay += w0 * v0.y + w1 * v1.y;
    }
    if (j < end) {
        int s0 = __builtin_nontemporal_load(&scsr[j]);
        float w0 = __builtin_nontemporal_load(&wcsr[j]);
        float2 v0 = __half22float2(h2[(size_t)s0 * 32 + u]);
        ax += w0 * v0.x;
        ay += w0 * v0.y;
    }
    ax += __shfl_xor(ax, 32);
    ay += __shfl_xor(ay, 32);
    if (eh == 0) {
        float inv = invden[d];
        float2 bb = b2_2[u];
        float hx = ax * inv + bb.x; hx = hx > 0.f ? hx : 0.f;
        float hy = ay * inv + bb.y; hy = hy > 0.f ? hy : 0.f;
        int g = batch[d];
        atomicAdd(&pooled[g * CC + u * 2], hx);
        atomicAdd(&pooled[g * CC + u * 2 + 1], hy);
    }
}

__global__ void final_kernel(const float* __restrict__ pooled, const float* __restrict__ cnt,
    const float* __restrict__ fc_w, const float* __restrict__ fc_b, float* __restrict__ out)
{
    int g = blockIdx.x, lane = threadIdx.x;
    float v = pooled[g * CC + lane] / fmaxf(cnt[g], 1.f) * fc_w[lane];
    v = waveReduceSum(v);
    if (lane == 0) out[g] = v + fc_b[0];
}

extern "C" void kernel_launch(void* const* d_in, const int* in_sizes, int n_in,
                              void* d_out, int out_size, void* d_ws, size_t ws_size,
                              hipStream_t stream)
{
    const float* x        = (const float*)d_in[0];
    const float* W1       = (const float*)d_in[1];
    const float* att_src1 = (const float*)d_in[2];
    const float* att_dst1 = (const float*)d_in[3];
    const float* b1       = (const float*)d_in[4];
    const float* W2       = (const float*)d_in[5];
    const float* att_src2 = (const float*)d_in[6];
    const float* att_dst2 = (const float*)d_in[7];
    const float* b2       = (const float*)d_in[8];
    const float* fc_w     = (const float*)d_in[9];
    const float* fc_b     = (const float*)d_in[10];
    const int*   ei       = (const int*)d_in[11];   // [2, E] -> src = ei, dst = ei + EE
    const int*   batch    = (const int*)d_in[12];
    float* out = (float*)d_out;

    char* p = (char*)d_ws;
    __half* W1t   = (__half*)p; p += (size_t)HC * FIN * sizeof(__half);  // 64 KB
    __half* W2t   = (__half*)p; p += (size_t)CC * HC * sizeof(__half);   // 32 KB
    __half* h1    = (__half*)p; p += (size_t)NN * HC * sizeof(__half);   // 25.6 MB
    __half* out1r = (__half*)p; p += (size_t)NN * HC * sizeof(__half);   // 25.6 MB
    __half* h2    = (__half*)p; p += (size_t)NN * CC * sizeof(__half);   // 6.4 MB
    float* wcsr1  = (float*)p;  p += (size_t)ET * HH * sizeof(float);    // 13.6 MB
    float* wcsr2  = (float*)p;  p += (size_t)ET * sizeof(float);         // 3.4 MB
    float* a_s1   = (float*)p;  p += (size_t)NN * HH * sizeof(float);
    float* a_d1   = (float*)p;  p += (size_t)NN * HH * sizeof(float);
    float* invden1= (float*)p;  p += (size_t)NN * HH * sizeof(float);
    float* a_s2   = (float*)p;  p += NN * sizeof(float);
    float* a_d2   = (float*)p;  p += NN * sizeof(float);
    float* invden2= (float*)p;  p += NN * sizeof(float);
    float* pooled = (float*)p;  p += (size_t)GG * CC * sizeof(float);    // pooled+cnt contiguous
    float* cnt    = (float*)p;  p += GG * sizeof(float);
    int* counts   = (int*)p;    p += NN * sizeof(int);
    int* rowptr   = (int*)p;    p += (NN + 1) * sizeof(int);
    int* cursor   = (int*)p;    p += NN * sizeof(int);
    int* scsr     = (int*)p;    p += ET * sizeof(int);
    int* bsum     = (int*)p;    p += SCAN_NB * sizeof(int);

    const int EB = (ET + 255) / 256;

    init0_kernel<<<256, 256, 0, stream>>>(counts, pooled);
    histcnt_kernel<<<EB, 256, 0, stream>>>(ei, counts, batch, cnt);
    cvtw_kernel<<<(HC * FIN + CC * HC) / 256, 256, 0, stream>>>(W1, W2, W1t, W2t);
    scanA_kernel<<<SCAN_NB, 256, 0, stream>>>(counts, bsum);
    scanB_kernel<<<1, 256, 0, stream>>>(bsum);
    scanC_kernel<<<SCAN_NB, 256, 0, stream>>>(counts, bsum, rowptr, cursor);
    fill_kernel<<<EB, 256, 0, stream>>>(ei, cursor, scsr);
    gemm1_mfma_kernel<<<(NN + 31) / 32, 256, 0, stream>>>(x, W1t, att_src1, att_dst1,
                                                          h1, a_s1, a_d1);
    attn1_kernel<<<NN / 4, 256, 0, stream>>>(rowptr, scsr, (const float4*)a_s1,
                                             (const float4*)a_d1, (float4*)wcsr1,
                                             (float4*)invden1);
    emsg1_gather_kernel<<<NN / 2, 256, 0, stream>>>(rowptr, scsr, wcsr1, invden1,
                                                    (const __half2*)h1, (const float2*)b1,
                                                    (__half2*)out1r);
    gemm2_mfma_kernel<<<(NN + 63) / 64, 256, 0, stream>>>(out1r, W2t, att_src2, att_dst2,
                                                          h2, a_s2, a_d2);
    attn2_kernel<<<NN / 4, 256, 0, stream>>>(rowptr, scsr, a_s2, a_d2, wcsr2, invden2);
    emsg2_gather_kernel<<<NN / 4, 256, 0, stream>>>(rowptr, scsr, wcsr2, invden2,
                                                    (const __half2*)h2, (const float2*)b2,
                                                    batch, pooled);
    final_kernel<<<GG, 64, 0, stream>>>(pooled, cnt, fc_w, fc_b, out);
}

// Round 8
// 360.726 us; speedup vs baseline: 4.1962x; 1.0894x over previous
//
#include <hip/hip_runtime.h>
#include <hip/hip_fp16.h>
#include <math.h>

#define NN 50000
#define FIN 128
#define HH 4
#define CC 64
#define HC (HH*CC)       // 256
#define GG 512
#define EE 800000
#define ET (EE + NN)     // 850000 edges incl. self-loops
#define NEG_SLOPE 0.2f
#define SCAN_NB 196      // ceil(NN/256)

typedef _Float16 half8 __attribute__((ext_vector_type(8)));
typedef float floatx4 __attribute__((ext_vector_type(4)));

__device__ __forceinline__ float waveReduceSum(float v) {
    #pragma unroll
    for (int off = 32; off > 0; off >>= 1) v += __shfl_xor(v, off);
    return v;
}

// zero counts / pooled / cnt (accumulated-into buffers; ws is not re-poisoned)
__global__ __launch_bounds__(256) void init0_kernel(int* __restrict__ counts,
                                                    float* __restrict__ pooled) {
    int i = blockIdx.x * 256 + threadIdx.x;
    int stride = gridDim.x * 256;
    for (int j = i; j < NN; j += stride) counts[j] = 0;
    for (int j = i; j < GG * CC + GG; j += stride) pooled[j] = 0.f;  // pooled then cnt contiguous
}

// histogram of dst + batch count, fused
__global__ __launch_bounds__(256) void histcnt_kernel(const int* __restrict__ ei,
                                                      int* __restrict__ counts,
                                                      const int* __restrict__ batch,
                                                      float* __restrict__ cnt) {
    int e = blockIdx.x * 256 + threadIdx.x;
    if (e < ET) {
        int d = (e < EE) ? ei[EE + e] : e - EE;
        atomicAdd(&counts[d], 1);
    }
    if (e < NN) atomicAdd(&cnt[batch[e]], 1.f);
}

// W1t[n][k] = fp16(W1[k][n]) (256x128) ; W2t[n][k] = fp16(W2[k][n]) (64x256)
__global__ __launch_bounds__(256) void cvtw_kernel(const float* __restrict__ W1,
                                                   const float* __restrict__ W2,
                                                   __half* __restrict__ W1t,
                                                   __half* __restrict__ W2t) {
    int i = blockIdx.x * 256 + threadIdx.x;   // grid exact: 192*256 = 49152
    if (i < HC * FIN) {
        int n = i >> 7, k = i & 127;
        W1t[i] = __float2half(W1[(size_t)k * HC + n]);
    } else {
        int i2 = i - HC * FIN;                // 0..16383
        int n = i2 >> 8, k = i2 & 255;
        W2t[i2] = __float2half(W2[(size_t)k * CC + n]);
    }
}

// ---- three-phase device-wide exclusive scan of counts[NN] ----
__global__ __launch_bounds__(256) void scanA_kernel(const int* __restrict__ counts,
                                                    int* __restrict__ bsum) {
    __shared__ int sh[256];
    int t = threadIdx.x;
    int i = blockIdx.x * 256 + t;
    sh[t] = (i < NN) ? counts[i] : 0;
    __syncthreads();
    #pragma unroll
    for (int off = 128; off > 0; off >>= 1) {
        if (t < off) sh[t] += sh[t + off];
        __syncthreads();
    }
    if (t == 0) bsum[blockIdx.x] = sh[0];
}

__global__ __launch_bounds__(256) void scanB_kernel(int* __restrict__ bsum) {
    __shared__ int sh[256];
    int t = threadIdx.x;
    int v = (t < SCAN_NB) ? bsum[t] : 0;
    sh[t] = v;
    __syncthreads();
    for (int off = 1; off < 256; off <<= 1) {
        int u = (t >= off) ? sh[t - off] : 0;
        __syncthreads();
        sh[t] += u;
        __syncthreads();
    }
    if (t < SCAN_NB) bsum[t] = sh[t] - v;   // exclusive
}

__global__ __launch_bounds__(256) void scanC_kernel(const int* __restrict__ counts,
                                                    const int* __restrict__ bsum,
                                                    int* __restrict__ rowptr,
                                                    int* __restrict__ cursor) {
    __shared__ int sh[256];
    int t = threadIdx.x;
    int i = blockIdx.x * 256 + t;
    int v = (i < NN) ? counts[i] : 0;
    sh[t] = v;
    __syncthreads();
    for (int off = 1; off < 256; off <<= 1) {
        int u = (t >= off) ? sh[t - off] : 0;
        __syncthreads();
        sh[t] += u;
        __syncthreads();
    }
    int excl = sh[t] - v + bsum[blockIdx.x];
    if (i < NN) { rowptr[i] = excl; cursor[i] = excl; }
    if (i == NN - 1) rowptr[NN] = excl + v;   // = ET
}

__global__ __launch_bounds__(256) void fill_kernel(const int* __restrict__ ei,
                                                   int* __restrict__ cursor,
                                                   int* __restrict__ scsr) {
    int e = blockIdx.x * 256 + threadIdx.x;
    if (e >= ET) return;
    int s, d;
    if (e < EE) { s = ei[e]; d = ei[EE + e]; } else { s = d = e - EE; }
    int pos = atomicAdd(&cursor[d], 1);
    scsr[pos] = s;
}

// h1 = x @ W1 via fp16 MFMA (f32 accum); fused a_s1/a_d1.
// A-tile (32 rows x 128 cols f32) staged in LDS with coalesced float4 loads;
// +4-float row pad -> 2-way bank aliasing (free).
__global__ __launch_bounds__(256) void gemm1_mfma_kernel(
    const float* __restrict__ x, const __half* __restrict__ W1t,
    const float* __restrict__ att_src1, const float* __restrict__ att_dst1,
    __half* __restrict__ h1, float* __restrict__ a_s1, float* __restrict__ a_d1)
{
    __shared__ __align__(16) float xs[32][FIN + 4];
    int t = threadIdx.x;
    int n0 = blockIdx.x * 32;
    #pragma unroll
    for (int i = 0; i < 4; ++i) {
        int idx = t + i * 256;             // 0..1023 float4 slots
        int row = idx >> 5, c4 = idx & 31;
        int m = n0 + row; if (m >= NN) m = NN - 1;
        float4 v = *(const float4*)(x + (size_t)m * FIN + c4 * 4);
        *(float4*)&xs[row][c4 * 4] = v;
    }
    __syncthreads();

    int w = t >> 6;                        // wave 0..3
    int l = t & 63;
    int nbase = n0 + (w >> 1) * 16;        // 16-node tile
    int chalf = (w & 1) * 128;             // column half
    int lm = l & 15, lb = l >> 4;
    int lrow = (w >> 1) * 16 + lm;

    half8 afrag[4];
    #pragma unroll
    for (int q = 0; q < 4; ++q) {
        float4 lo = *(const float4*)&xs[lrow][q * 32 + lb * 8];
        float4 hi = *(const float4*)&xs[lrow][q * 32 + lb * 8 + 4];
        half8 f;
        #pragma unroll
        for (int i = 0; i < 4; ++i) {
            f[i] = (_Float16)(&lo.x)[i];
            f[4 + i] = (_Float16)(&hi.x)[i];
        }
        afrag[q] = f;
    }
    floatx4 acc[8];
    #pragma unroll
    for (int tt = 0; tt < 8; ++tt) acc[tt] = (floatx4){0.f, 0.f, 0.f, 0.f};

    const __half* wt = W1t + (size_t)(chalf + lm) * FIN + lb * 8;
    #pragma unroll
    for (int tt = 0; tt < 8; ++tt) {
        const __half* wtt = wt + (size_t)tt * 16 * FIN;
        #pragma unroll
        for (int q = 0; q < 4; ++q) {
            half8 b = *(const half8*)(wtt + q * 32);
            acc[tt] = __builtin_amdgcn_mfma_f32_16x16x32_f16(afrag[q], b, acc[tt], 0, 0, 0);
        }
    }
    #pragma unroll
    for (int hh = 0; hh < 2; ++hh) {
        float as_p[4] = {0.f, 0.f, 0.f, 0.f};
        float ad_p[4] = {0.f, 0.f, 0.f, 0.f};
        #pragma unroll
        for (int tt = 0; tt < 4; ++tt) {
            int ti = hh * 4 + tt;
            int col = chalf + ti * 16 + lm;
            float asw = att_src1[col], adw = att_dst1[col];
            #pragma unroll
            for (int r = 0; r < 4; ++r) {
                int n = nbase + lb * 4 + r;
                float v = acc[ti][r];
                if (n < NN) h1[(size_t)n * HC + col] = __float2half(v);
                as_p[r] += v * asw;
                ad_p[r] += v * adw;
            }
        }
        #pragma unroll
        for (int off = 1; off < 16; off <<= 1) {
            #pragma unroll
            for (int r = 0; r < 4; ++r) {
                as_p[r] += __shfl_xor(as_p[r], off);
                ad_p[r] += __shfl_xor(ad_p[r], off);
            }
        }
        if (lm == 0) {
            int head = (chalf >> 6) + hh;
            #pragma unroll
            for (int r = 0; r < 4; ++r) {
                int n = nbase + lb * 4 + r;
                if (n < NN) { a_s1[n * HH + head] = as_p[r]; a_d1[n * HH + head] = ad_p[r]; }
            }
        }
    }
}

// per-dst edge-lane-parallel weights, layer 1. wave per dst, 4 dst/block.
__global__ __launch_bounds__(256) void attn1_kernel(
    const int* __restrict__ rowptr, const int* __restrict__ scsr,
    const float4* __restrict__ a_s4, const float4* __restrict__ a_d4,
    float4* __restrict__ wcsr4, float4* __restrict__ invden4)
{
    int d = blockIdx.x * 4 + (threadIdx.x >> 6);   // grid exact: 12500*4
    int lane = threadIdx.x & 63;
    int start = rowptr[d], end = rowptr[d + 1];
    float4 ad = a_d4[d];
    float den0 = 0.f, den1 = 0.f, den2 = 0.f, den3 = 0.f;
    for (int j = start + lane; j < end; j += 64) {
        float4 as = a_s4[scsr[j]];
        float a0 = as.x + ad.x, a1 = as.y + ad.y, a2 = as.z + ad.z, a3 = as.w + ad.w;
        a0 = (a0 > 0.f) ? a0 : NEG_SLOPE * a0;
        a1 = (a1 > 0.f) ? a1 : NEG_SLOPE * a1;
        a2 = (a2 > 0.f) ? a2 : NEG_SLOPE * a2;
        a3 = (a3 > 0.f) ? a3 : NEG_SLOPE * a3;
        float w0 = expf(a0), w1 = expf(a1), w2 = expf(a2), w3 = expf(a3);
        wcsr4[j] = make_float4(w0, w1, w2, w3);
        den0 += w0; den1 += w1; den2 += w2; den3 += w3;
    }
    den0 = waveReduceSum(den0);
    den1 = waveReduceSum(den1);
    den2 = waveReduceSum(den2);
    den3 = waveReduceSum(den3);
    if (lane == 0)
        invden4[d] = make_float4(1.f / (den0 + 1e-16f), 1.f / (den1 + 1e-16f),
                                 1.f / (den2 + 1e-16f), 1.f / (den3 + 1e-16f));
}

// gather-accumulate layer 1 + fused bias1/relu, fp16 out. 2 dst per 256-thread block.
__global__ __launch_bounds__(256) void emsg1_gather_kernel(
    const int* __restrict__ rowptr, const int* __restrict__ scsr,
    const float* __restrict__ wcsr, const float* __restrict__ invden,
    const __half2* __restrict__ h1, const float2* __restrict__ b1_2,
    __half2* __restrict__ out1r)
{
    int t = threadIdx.x;
    int g = t >> 7;            // which dst in block
    int u = t & 127;           // channel-pair index (2u, 2u+1)
    int d = blockIdx.x * 2 + g;   // grid exact: 25000*2
    int head = u >> 5;
    int start = rowptr[d], end = rowptr[d + 1];
    float ax = 0.f, ay = 0.f;
    int j = start;
    for (; j + 3 < end; j += 4) {
        int s0 = scsr[j], s1 = scsr[j + 1], s2 = scsr[j + 2], s3 = scsr[j + 3];
        float w0 = wcsr[j * 4 + head];
        float w1 = wcsr[(j + 1) * 4 + head];
        float w2 = wcsr[(j + 2) * 4 + head];
        float w3 = wcsr[(j + 3) * 4 + head];
        float2 v0 = __half22float2(h1[(size_t)s0 * 128 + u]);
        float2 v1 = __half22float2(h1[(size_t)s1 * 128 + u]);
        float2 v2 = __half22float2(h1[(size_t)s2 * 128 + u]);
        float2 v3 = __half22float2(h1[(size_t)s3 * 128 + u]);
        ax += w0 * v0.x + w1 * v1.x + w2 * v2.x + w3 * v3.x;
        ay += w0 * v0.y + w1 * v1.y + w2 * v2.y + w3 * v3.y;
    }
    for (; j < end; ++j) {
        int s0 = scsr[j];
        float w0 = wcsr[j * 4 + head];
        float2 v0 = __half22float2(h1[(size_t)s0 * 128 + u]);
        ax += w0 * v0.x;
        ay += w0 * v0.y;
    }
    float inv = invden[d * 4 + head];
    float2 bb = b1_2[u];
    float rx = ax * inv + bb.x; rx = rx > 0.f ? rx : 0.f;
    float ry = ay * inv + bb.y; ry = ry > 0.f ? ry : 0.f;
    out1r[(size_t)d * 128 + u] = __floats2half2_rn(rx, ry);
}

// h2 = out1r @ W2 via fp16 MFMA; fused a_s2/a_d2. 64 nodes/block, 4 waves.
// A-tile (64 rows x 256 cols fp16) staged in LDS with coalesced 16B loads; +8-half pad.
__global__ __launch_bounds__(256) void gemm2_mfma_kernel(
    const __half* __restrict__ out1r, const __half* __restrict__ W2t,
    const float* __restrict__ att_src2, const float* __restrict__ att_dst2,
    __half* __restrict__ h2, float* __restrict__ a_s2, float* __restrict__ a_d2)
{
    __shared__ __align__(16) __half ys[64][HC + 8];
    int t = threadIdx.x;
    int n0 = blockIdx.x * 64;
    #pragma unroll
    for (int i = 0; i < 8; ++i) {
        int idx = t + i * 256;             // 0..2047 half8 slots
        int row = idx >> 5, c8 = idx & 31;
        int m = n0 + row; if (m >= NN) m = NN - 1;
        *(half8*)&ys[row][c8 * 8] = *(const half8*)(out1r + (size_t)m * HC + c8 * 8);
    }
    __syncthreads();

    int w = t >> 6;
    int l = t & 63;
    int nbase = n0 + w * 16;
    int lm = l & 15, lb = l >> 4;
    int lrow = w * 16 + lm;

    half8 afrag[8];
    #pragma unroll
    for (int q = 0; q < 8; ++q) afrag[q] = *(const half8*)&ys[lrow][q * 32 + lb * 8];

    floatx4 acc[4];
    #pragma unroll
    for (int tt = 0; tt < 4; ++tt) acc[tt] = (floatx4){0.f, 0.f, 0.f, 0.f};

    const __half* wt = W2t + (size_t)lm * HC + lb * 8;
    #pragma unroll
    for (int tt = 0; tt < 4; ++tt) {
        const __half* wtt = wt + (size_t)tt * 16 * HC;
        #pragma unroll
        for (int q = 0; q < 8; ++q) {
            half8 b = *(const half8*)(wtt + q * 32);
            acc[tt] = __builtin_amdgcn_mfma_f32_16x16x32_f16(afrag[q], b, acc[tt], 0, 0, 0);
        }
    }
    float as_p[4] = {0.f, 0.f, 0.f, 0.f};
    float ad_p[4] = {0.f, 0.f, 0.f, 0.f};
    #pragma unroll
    for (int tt = 0; tt < 4; ++tt) {
        int col = tt * 16 + lm;
        float asw = att_src2[col], adw = att_dst2[col];
        #pragma unroll
        for (int r = 0; r < 4; ++r) {
            int n = nbase + lb * 4 + r;
            float v = acc[tt][r];
            if (n < NN) h2[(size_t)n * CC + col] = __float2half(v);
            as_p[r] += v * asw;
            ad_p[r] += v * adw;
        }
    }
    #pragma unroll
    for (int off = 1; off < 16; off <<= 1) {
        #pragma unroll
        for (int r = 0; r < 4; ++r) {
            as_p[r] += __shfl_xor(as_p[r], off);
            ad_p[r] += __shfl_xor(ad_p[r], off);
        }
    }
    if (lm == 0) {
        #pragma unroll
        for (int r = 0; r < 4; ++r) {
            int n = nbase + lb * 4 + r;
            if (n < NN) { a_s2[n] = as_p[r]; a_d2[n] = ad_p[r]; }
        }
    }
}

// per-dst edge-lane-parallel weights, layer 2 (1 head). wave per dst, 4/block.
__global__ __launch_bounds__(256) void attn2_kernel(
    const int* __restrict__ rowptr, const int* __restrict__ scsr,
    const float* __restrict__ a_s, const float* __restrict__ a_d,
    float* __restrict__ wcsr, float* __restrict__ invden)
{
    int d = blockIdx.x * 4 + (threadIdx.x >> 6);
    int lane = threadIdx.x & 63;
    int start = rowptr[d], end = rowptr[d + 1];
    float ad = a_d[d];
    float den = 0.f;
    for (int j = start + lane; j < end; j += 64) {
        float a = a_s[scsr[j]] + ad;
        a = (a > 0.f) ? a : NEG_SLOPE * a;
        float w = expf(a);
        wcsr[j] = w;
        den += w;
    }
    den = waveReduceSum(den);
    if (lane == 0) invden[d] = 1.f / (den + 1e-16f);
}

// gather layer 2 (fp16 h2) + fused relu/bias/mean-pool scatter.
// 1 wave/dst, 4/block; lanes: u=ch-pair (0..31), eh=edge parity.
__global__ __launch_bounds__(256) void emsg2_gather_kernel(
    const int* __restrict__ rowptr, const int* __restrict__ scsr,
    const float* __restrict__ wcsr, const float* __restrict__ invden,
    const __half2* __restrict__ h2, const float2* __restrict__ b2_2,
    const int* __restrict__ batch, float* __restrict__ pooled)
{
    int d = blockIdx.x * 4 + (threadIdx.x >> 6);
    int lane = threadIdx.x & 63;
    int u = lane & 31;
    int eh = lane >> 5;
    int start = rowptr[d], end = rowptr[d + 1];
    float ax = 0.f, ay = 0.f;
    int j = start + eh;
    for (; j + 2 < end; j += 4) {
        int s0 = scsr[j], s1 = scsr[j + 2];
        float w0 = wcsr[j], w1 = wcsr[j + 2];
        float2 v0 = __half22float2(h2[(size_t)s0 * 32 + u]);
        float2 v1 = __half22float2(h2[(size_t)s1 * 32 + u]);
        ax += w0 * v0.x + w1 * v1.x;
        ay += w0 * v0.y + w1 * v1.y;
    }
    if (j < end) {
        int s0 = scsr[j];
        float w0 = wcsr[j];
        float2 v0 = __half22float2(h2[(size_t)s0 * 32 + u]);
        ax += w0 * v0.x;
        ay += w0 * v0.y;
    }
    ax += __shfl_xor(ax, 32);
    ay += __shfl_xor(ay, 32);
    if (eh == 0) {
        float inv = invden[d];
        float2 bb = b2_2[u];
        float hx = ax * inv + bb.x; hx = hx > 0.f ? hx : 0.f;
        float hy = ay * inv + bb.y; hy = hy > 0.f ? hy : 0.f;
        int g = batch[d];
        atomicAdd(&pooled[g * CC + u * 2], hx);
        atomicAdd(&pooled[g * CC + u * 2 + 1], hy);
    }
}

__global__ void final_kernel(const float* __restrict__ pooled, const float* __restrict__ cnt,
    const float* __restrict__ fc_w, const float* __restrict__ fc_b, float* __restrict__ out)
{
    int g = blockIdx.x, lane = threadIdx.x;
    float v = pooled[g * CC + lane] / fmaxf(cnt[g], 1.f) * fc_w[lane];
    v = waveReduceSum(v);
    if (lane == 0) out[g] = v + fc_b[0];
}

extern "C" void kernel_launch(void* const* d_in, const int* in_sizes, int n_in,
                              void* d_out, int out_size, void* d_ws, size_t ws_size,
                              hipStream_t stream)
{
    const float* x        = (const float*)d_in[0];
    const float* W1       = (const float*)d_in[1];
    const float* att_src1 = (const float*)d_in[2];
    const float* att_dst1 = (const float*)d_in[3];
    const float* b1       = (const float*)d_in[4];
    const float* W2       = (const float*)d_in[5];
    const float* att_src2 = (const float*)d_in[6];
    const float* att_dst2 = (const float*)d_in[7];
    const float* b2       = (const float*)d_in[8];
    const float* fc_w     = (const float*)d_in[9];
    const float* fc_b     = (const float*)d_in[10];
    const int*   ei       = (const int*)d_in[11];   // [2, E] -> src = ei, dst = ei + EE
    const int*   batch    = (const int*)d_in[12];
    float* out = (float*)d_out;

    char* p = (char*)d_ws;
    __half* W1t   = (__half*)p; p += (size_t)HC * FIN * sizeof(__half);  // 64 KB
    __half* W2t   = (__half*)p; p += (size_t)CC * HC * sizeof(__half);   // 32 KB
    __half* h1    = (__half*)p; p += (size_t)NN * HC * sizeof(__half);   // 25.6 MB
    __half* out1r = (__half*)p; p += (size_t)NN * HC * sizeof(__half);   // 25.6 MB
    __half* h2    = (__half*)p; p += (size_t)NN * CC * sizeof(__half);   // 6.4 MB
    float* wcsr1  = (float*)p;  p += (size_t)ET * HH * sizeof(float);    // 13.6 MB
    float* wcsr2  = (float*)p;  p += (size_t)ET * sizeof(float);         // 3.4 MB
    float* a_s1   = (float*)p;  p += (size_t)NN * HH * sizeof(float);
    float* a_d1   = (float*)p;  p += (size_t)NN * HH * sizeof(float);
    float* invden1= (float*)p;  p += (size_t)NN * HH * sizeof(float);
    float* a_s2   = (float*)p;  p += NN * sizeof(float);
    float* a_d2   = (float*)p;  p += NN * sizeof(float);
    float* invden2= (float*)p;  p += NN * sizeof(float);
    float* pooled = (float*)p;  p += (size_t)GG * CC * sizeof(float);    // pooled+cnt contiguous
    float* cnt    = (float*)p;  p += GG * sizeof(float);
    int* counts   = (int*)p;    p += NN * sizeof(int);
    int* rowptr   = (int*)p;    p += (NN + 1) * sizeof(int);
    int* cursor   = (int*)p;    p += NN * sizeof(int);
    int* scsr     = (int*)p;    p += ET * sizeof(int);
    int* bsum     = (int*)p;    p += SCAN_NB * sizeof(int);

    const int EB = (ET + 255) / 256;

    init0_kernel<<<256, 256, 0, stream>>>(counts, pooled);
    histcnt_kernel<<<EB, 256, 0, stream>>>(ei, counts, batch, cnt);
    cvtw_kernel<<<(HC * FIN + CC * HC) / 256, 256, 0, stream>>>(W1, W2, W1t, W2t);
    scanA_kernel<<<SCAN_NB, 256, 0, stream>>>(counts, bsum);
    scanB_kernel<<<1, 256, 0, stream>>>(bsum);
    scanC_kernel<<<SCAN_NB, 256, 0, stream>>>(counts, bsum, rowptr, cursor);
    fill_kernel<<<EB, 256, 0, stream>>>(ei, cursor, scsr);
    gemm1_mfma_kernel<<<(NN + 31) / 32, 256, 0, stream>>>(x, W1t, att_src1, att_dst1,
                                                          h1, a_s1, a_d1);
    attn1_kernel<<<NN / 4, 256, 0, stream>>>(rowptr, scsr, (const float4*)a_s1,
                                             (const float4*)a_d1, (float4*)wcsr1,
                                             (float4*)invden1);
    emsg1_gather_kernel<<<NN / 2, 256, 0, stream>>>(rowptr, scsr, wcsr1, invden1,
                                                    (const __half2*)h1, (const float2*)b1,
                                                    (__half2*)out1r);
    gemm2_mfma_kernel<<<(NN + 63) / 64, 256, 0, stream>>>(out1r, W2t, att_src2, att_dst2,
                                                          h2, a_s2, a_d2);
    attn2_kernel<<<NN / 4, 256, 0, stream>>>(rowptr, scsr, a_s2, a_d2, wcsr2, invden2);
    emsg2_gather_kernel<<<NN / 4, 256, 0, stream>>>(rowptr, scsr, wcsr2, invden2,
                                                    (const __half2*)h2, (const float2*)b2,
                                                    batch, pooled);
    final_kernel<<<GG, 64, 0, stream>>>(pooled, cnt, fc_w, fc_b, out);
}

// Round 9
// 340.754 us; speedup vs baseline: 4.4422x; 1.0586x over previous
//
#include <hip/hip_runtime.h>
#include <hip/hip_fp16.h>
#include <math.h>

#define NN 50000
#define FIN 128
#define HH 4
#define CC 64
#define HC (HH*CC)       // 256
#define GG 512
#define EE 800000
#define ET (EE + NN)     // 850000 edges incl. self-loops
#define NEG_SLOPE 0.2f
#define SCAN_NB 196      // ceil(NN/256)

typedef _Float16 half8 __attribute__((ext_vector_type(8)));
typedef _Float16 half4 __attribute__((ext_vector_type(4)));
typedef float floatx4 __attribute__((ext_vector_type(4)));

__device__ __forceinline__ float waveReduceSum(float v) {
    #pragma unroll
    for (int off = 32; off > 0; off >>= 1) v += __shfl_xor(v, off);
    return v;
}

// zero counts / pooled / cnt (accumulated-into buffers; ws is not re-poisoned)
__global__ __launch_bounds__(256) void init0_kernel(int* __restrict__ counts,
                                                    float* __restrict__ pooled) {
    int i = blockIdx.x * 256 + threadIdx.x;
    int stride = gridDim.x * 256;
    for (int j = i; j < NN; j += stride) counts[j] = 0;
    for (int j = i; j < GG * CC + GG; j += stride) pooled[j] = 0.f;  // pooled then cnt contiguous
}

// histogram of dst + batch count, fused
__global__ __launch_bounds__(256) void histcnt_kernel(const int* __restrict__ ei,
                                                      int* __restrict__ counts,
                                                      const int* __restrict__ batch,
                                                      float* __restrict__ cnt) {
    int e = blockIdx.x * 256 + threadIdx.x;
    if (e < ET) {
        int d = (e < EE) ? ei[EE + e] : e - EE;
        atomicAdd(&counts[d], 1);
    }
    if (e < NN) atomicAdd(&cnt[batch[e]], 1.f);
}

// W1t[n][k] = fp16(W1[k][n]) (256x128) ; W2t[n][k] = fp16(W2[k][n]) (64x256)
__global__ __launch_bounds__(256) void cvtw_kernel(const float* __restrict__ W1,
                                                   const float* __restrict__ W2,
                                                   __half* __restrict__ W1t,
                                                   __half* __restrict__ W2t) {
    int i = blockIdx.x * 256 + threadIdx.x;   // grid exact: 192*256 = 49152
    if (i < HC * FIN) {
        int n = i >> 7, k = i & 127;
        W1t[i] = __float2half(W1[(size_t)k * HC + n]);
    } else {
        int i2 = i - HC * FIN;                // 0..16383
        int n = i2 >> 8, k = i2 & 255;
        W2t[i2] = __float2half(W2[(size_t)k * CC + n]);
    }
}

// ---- three-phase device-wide exclusive scan of counts[NN] ----
__global__ __launch_bounds__(256) void scanA_kernel(const int* __restrict__ counts,
                                                    int* __restrict__ bsum) {
    __shared__ int sh[256];
    int t = threadIdx.x;
    int i = blockIdx.x * 256 + t;
    sh[t] = (i < NN) ? counts[i] : 0;
    __syncthreads();
    #pragma unroll
    for (int off = 128; off > 0; off >>= 1) {
        if (t < off) sh[t] += sh[t + off];
        __syncthreads();
    }
    if (t == 0) bsum[blockIdx.x] = sh[0];
}

__global__ __launch_bounds__(256) void scanB_kernel(int* __restrict__ bsum) {
    __shared__ int sh[256];
    int t = threadIdx.x;
    int v = (t < SCAN_NB) ? bsum[t] : 0;
    sh[t] = v;
    __syncthreads();
    for (int off = 1; off < 256; off <<= 1) {
        int u = (t >= off) ? sh[t - off] : 0;
        __syncthreads();
        sh[t] += u;
        __syncthreads();
    }
    if (t < SCAN_NB) bsum[t] = sh[t] - v;   // exclusive
}

__global__ __launch_bounds__(256) void scanC_kernel(const int* __restrict__ counts,
                                                    const int* __restrict__ bsum,
                                                    int* __restrict__ rowptr,
                                                    int* __restrict__ cursor) {
    __shared__ int sh[256];
    int t = threadIdx.x;
    int i = blockIdx.x * 256 + t;
    int v = (i < NN) ? counts[i] : 0;
    sh[t] = v;
    __syncthreads();
    for (int off = 1; off < 256; off <<= 1) {
        int u = (t >= off) ? sh[t - off] : 0;
        __syncthreads();
        sh[t] += u;
        __syncthreads();
    }
    int excl = sh[t] - v + bsum[blockIdx.x];
    if (i < NN) { rowptr[i] = excl; cursor[i] = excl; }
    if (i == NN - 1) rowptr[NN] = excl + v;   // = ET
}

__global__ __launch_bounds__(256) void fill_kernel(const int* __restrict__ ei,
                                                   int* __restrict__ cursor,
                                                   int* __restrict__ scsr) {
    int e = blockIdx.x * 256 + threadIdx.x;
    if (e >= ET) return;
    int s, d;
    if (e < EE) { s = ei[e]; d = ei[EE + e]; } else { s = d = e - EE; }
    int pos = atomicAdd(&cursor[d], 1);
    scsr[pos] = s;
}

// h1 = x @ W1 via fp16 MFMA (f32 accum); fused a_s1/a_d1.
// A-tile staged in LDS with coalesced float4 loads; +4-float row pad.
__global__ __launch_bounds__(256) void gemm1_mfma_kernel(
    const float* __restrict__ x, const __half* __restrict__ W1t,
    const float* __restrict__ att_src1, const float* __restrict__ att_dst1,
    __half* __restrict__ h1, float* __restrict__ a_s1, float* __restrict__ a_d1)
{
    __shared__ __align__(16) float xs[32][FIN + 4];
    int t = threadIdx.x;
    int n0 = blockIdx.x * 32;
    #pragma unroll
    for (int i = 0; i < 4; ++i) {
        int idx = t + i * 256;             // 0..1023 float4 slots
        int row = idx >> 5, c4 = idx & 31;
        int m = n0 + row; if (m >= NN) m = NN - 1;
        float4 v = *(const float4*)(x + (size_t)m * FIN + c4 * 4);
        *(float4*)&xs[row][c4 * 4] = v;
    }
    __syncthreads();

    int w = t >> 6;                        // wave 0..3
    int l = t & 63;
    int nbase = n0 + (w >> 1) * 16;        // 16-node tile
    int chalf = (w & 1) * 128;             // column half
    int lm = l & 15, lb = l >> 4;
    int lrow = (w >> 1) * 16 + lm;

    half8 afrag[4];
    #pragma unroll
    for (int q = 0; q < 4; ++q) {
        float4 lo = *(const float4*)&xs[lrow][q * 32 + lb * 8];
        float4 hi = *(const float4*)&xs[lrow][q * 32 + lb * 8 + 4];
        half8 f;
        #pragma unroll
        for (int i = 0; i < 4; ++i) {
            f[i] = (_Float16)(&lo.x)[i];
            f[4 + i] = (_Float16)(&hi.x)[i];
        }
        afrag[q] = f;
    }
    floatx4 acc[8];
    #pragma unroll
    for (int tt = 0; tt < 8; ++tt) acc[tt] = (floatx4){0.f, 0.f, 0.f, 0.f};

    const __half* wt = W1t + (size_t)(chalf + lm) * FIN + lb * 8;
    #pragma unroll
    for (int tt = 0; tt < 8; ++tt) {
        const __half* wtt = wt + (size_t)tt * 16 * FIN;
        #pragma unroll
        for (int q = 0; q < 4; ++q) {
            half8 b = *(const half8*)(wtt + q * 32);
            acc[tt] = __builtin_amdgcn_mfma_f32_16x16x32_f16(afrag[q], b, acc[tt], 0, 0, 0);
        }
    }
    #pragma unroll
    for (int hh = 0; hh < 2; ++hh) {
        float as_p[4] = {0.f, 0.f, 0.f, 0.f};
        float ad_p[4] = {0.f, 0.f, 0.f, 0.f};
        #pragma unroll
        for (int tt = 0; tt < 4; ++tt) {
            int ti = hh * 4 + tt;
            int col = chalf + ti * 16 + lm;
            float asw = att_src1[col], adw = att_dst1[col];
            #pragma unroll
            for (int r = 0; r < 4; ++r) {
                int n = nbase + lb * 4 + r;
                float v = acc[ti][r];
                if (n < NN) h1[(size_t)n * HC + col] = __float2half(v);
                as_p[r] += v * asw;
                ad_p[r] += v * adw;
            }
        }
        #pragma unroll
        for (int off = 1; off < 16; off <<= 1) {
            #pragma unroll
            for (int r = 0; r < 4; ++r) {
                as_p[r] += __shfl_xor(as_p[r], off);
                ad_p[r] += __shfl_xor(ad_p[r], off);
            }
        }
        if (lm == 0) {
            int head = (chalf >> 6) + hh;
            #pragma unroll
            for (int r = 0; r < 4; ++r) {
                int n = nbase + lb * 4 + r;
                if (n < NN) { a_s1[n * HH + head] = as_p[r]; a_d1[n * HH + head] = ad_p[r]; }
            }
        }
    }
}

// fused weight + gather layer 1 + bias/relu, fp16 out. 1 wave/dst, 4 dst/block.
// lane l: channels 4l..4l+3 (half4); head = l>>4; weight computed inline
// (wave-wide: 1 broadcast a_s load + 1 exp per edge); den per-lane (no reduce).
__global__ __launch_bounds__(256) void emsg1_kernel(
    const int* __restrict__ rowptr, const int* __restrict__ scsr,
    const float* __restrict__ a_s, const float* __restrict__ a_d,
    const half4* __restrict__ h1v, const float* __restrict__ b1,
    half4* __restrict__ out1v)
{
    int d = blockIdx.x * 4 + (threadIdx.x >> 6);   // grid exact: 12500*4
    int l = threadIdx.x & 63;
    int head = l >> 4;
    int start = rowptr[d], end = rowptr[d + 1];
    float ad = a_d[d * HH + head];
    float den = 0.f;
    float a0 = 0.f, a1 = 0.f, a2 = 0.f, a3 = 0.f;
    int j = start;
    for (; j + 1 < end; j += 2) {
        int s0 = scsr[j], s1 = scsr[j + 1];
        float e0 = a_s[s0 * HH + head] + ad;
        float e1 = a_s[s1 * HH + head] + ad;
        e0 = (e0 > 0.f) ? e0 : NEG_SLOPE * e0;
        e1 = (e1 > 0.f) ? e1 : NEG_SLOPE * e1;
        float w0 = __expf(e0), w1 = __expf(e1);
        half4 v0 = h1v[(size_t)s0 * 64 + l];
        half4 v1 = h1v[(size_t)s1 * 64 + l];
        den += w0 + w1;
        a0 += w0 * (float)v0[0] + w1 * (float)v1[0];
        a1 += w0 * (float)v0[1] + w1 * (float)v1[1];
        a2 += w0 * (float)v0[2] + w1 * (float)v1[2];
        a3 += w0 * (float)v0[3] + w1 * (float)v1[3];
    }
    if (j < end) {
        int s0 = scsr[j];
        float e0 = a_s[s0 * HH + head] + ad;
        e0 = (e0 > 0.f) ? e0 : NEG_SLOPE * e0;
        float w0 = __expf(e0);
        half4 v0 = h1v[(size_t)s0 * 64 + l];
        den += w0;
        a0 += w0 * (float)v0[0];
        a1 += w0 * (float)v0[1];
        a2 += w0 * (float)v0[2];
        a3 += w0 * (float)v0[3];
    }
    float inv = 1.f / (den + 1e-16f);
    float4 bb = *(const float4*)(b1 + l * 4);
    float r0 = a0 * inv + bb.x; r0 = r0 > 0.f ? r0 : 0.f;
    float r1 = a1 * inv + bb.y; r1 = r1 > 0.f ? r1 : 0.f;
    float r2 = a2 * inv + bb.z; r2 = r2 > 0.f ? r2 : 0.f;
    float r3 = a3 * inv + bb.w; r3 = r3 > 0.f ? r3 : 0.f;
    half4 o;
    o[0] = (_Float16)r0; o[1] = (_Float16)r1; o[2] = (_Float16)r2; o[3] = (_Float16)r3;
    out1v[(size_t)d * 64 + l] = o;
}

// h2 = out1r @ W2 via fp16 MFMA; fused a_s2/a_d2. 64 nodes/block, 4 waves.
__global__ __launch_bounds__(256) void gemm2_mfma_kernel(
    const __half* __restrict__ out1r, const __half* __restrict__ W2t,
    const float* __restrict__ att_src2, const float* __restrict__ att_dst2,
    __half* __restrict__ h2, float* __restrict__ a_s2, float* __restrict__ a_d2)
{
    __shared__ __align__(16) __half ys[64][HC + 8];
    int t = threadIdx.x;
    int n0 = blockIdx.x * 64;
    #pragma unroll
    for (int i = 0; i < 8; ++i) {
        int idx = t + i * 256;             // 0..2047 half8 slots
        int row = idx >> 5, c8 = idx & 31;
        int m = n0 + row; if (m >= NN) m = NN - 1;
        *(half8*)&ys[row][c8 * 8] = *(const half8*)(out1r + (size_t)m * HC + c8 * 8);
    }
    __syncthreads();

    int w = t >> 6;
    int l = t & 63;
    int nbase = n0 + w * 16;
    int lm = l & 15, lb = l >> 4;
    int lrow = w * 16 + lm;

    half8 afrag[8];
    #pragma unroll
    for (int q = 0; q < 8; ++q) afrag[q] = *(const half8*)&ys[lrow][q * 32 + lb * 8];

    floatx4 acc[4];
    #pragma unroll
    for (int tt = 0; tt < 4; ++tt) acc[tt] = (floatx4){0.f, 0.f, 0.f, 0.f};

    const __half* wt = W2t + (size_t)lm * HC + lb * 8;
    #pragma unroll
    for (int tt = 0; tt < 4; ++tt) {
        const __half* wtt = wt + (size_t)tt * 16 * HC;
        #pragma unroll
        for (int q = 0; q < 8; ++q) {
            half8 b = *(const half8*)(wtt + q * 32);
            acc[tt] = __builtin_amdgcn_mfma_f32_16x16x32_f16(afrag[q], b, acc[tt], 0, 0, 0);
        }
    }
    float as_p[4] = {0.f, 0.f, 0.f, 0.f};
    float ad_p[4] = {0.f, 0.f, 0.f, 0.f};
    #pragma unroll
    for (int tt = 0; tt < 4; ++tt) {
        int col = tt * 16 + lm;
        float asw = att_src2[col], adw = att_dst2[col];
        #pragma unroll
        for (int r = 0; r < 4; ++r) {
            int n = nbase + lb * 4 + r;
            float v = acc[tt][r];
            if (n < NN) h2[(size_t)n * CC + col] = __float2half(v);
            as_p[r] += v * asw;
            ad_p[r] += v * adw;
        }
    }
    #pragma unroll
    for (int off = 1; off < 16; off <<= 1) {
        #pragma unroll
        for (int r = 0; r < 4; ++r) {
            as_p[r] += __shfl_xor(as_p[r], off);
            ad_p[r] += __shfl_xor(ad_p[r], off);
        }
    }
    if (lm == 0) {
        #pragma unroll
        for (int r = 0; r < 4; ++r) {
            int n = nbase + lb * 4 + r;
            if (n < NN) { a_s2[n] = as_p[r]; a_d2[n] = ad_p[r]; }
        }
    }
}

// fused weight + gather layer 2 + relu/bias/mean-pool scatter. 1 wave/dst, 4/block.
// lane: u = half4 channel (0..15), es = edge slot (0..3).
__global__ __launch_bounds__(256) void emsg2_kernel(
    const int* __restrict__ rowptr, const int* __restrict__ scsr,
    const float* __restrict__ a_s, const float* __restrict__ a_d,
    const half4* __restrict__ h2v, const float* __restrict__ b2,
    const int* __restrict__ batch, float* __restrict__ pooled)
{
    int d = blockIdx.x * 4 + (threadIdx.x >> 6);
    int l = threadIdx.x & 63;
    int u = l & 15;
    int es = l >> 4;
    int start = rowptr[d], end = rowptr[d + 1];
    float ad = a_d[d];
    float den = 0.f;
    float a0 = 0.f, a1 = 0.f, a2 = 0.f, a3 = 0.f;
    for (int j = start + es; j < end; j += 4) {
        int s = scsr[j];
        float e = a_s[s] + ad;
        e = (e > 0.f) ? e : NEG_SLOPE * e;
        float w = __expf(e);
        half4 v = h2v[(size_t)s * 16 + u];
        den += w;
        a0 += w * (float)v[0];
        a1 += w * (float)v[1];
        a2 += w * (float)v[2];
        a3 += w * (float)v[3];
    }
    #pragma unroll
    for (int off = 16; off < 64; off <<= 1) {
        den += __shfl_xor(den, off);
        a0 += __shfl_xor(a0, off);
        a1 += __shfl_xor(a1, off);
        a2 += __shfl_xor(a2, off);
        a3 += __shfl_xor(a3, off);
    }
    if (es == 0) {
        float inv = 1.f / (den + 1e-16f);
        float4 bb = *(const float4*)(b2 + u * 4);
        float h0 = a0 * inv + bb.x; h0 = h0 > 0.f ? h0 : 0.f;
        float h1 = a1 * inv + bb.y; h1 = h1 > 0.f ? h1 : 0.f;
        float h2 = a2 * inv + bb.z; h2 = h2 > 0.f ? h2 : 0.f;
        float h3 = a3 * inv + bb.w; h3 = h3 > 0.f ? h3 : 0.f;
        int g = batch[d];
        atomicAdd(&pooled[g * CC + u * 4], h0);
        atomicAdd(&pooled[g * CC + u * 4 + 1], h1);
        atomicAdd(&pooled[g * CC + u * 4 + 2], h2);
        atomicAdd(&pooled[g * CC + u * 4 + 3], h3);
    }
}

__global__ void final_kernel(const float* __restrict__ pooled, const float* __restrict__ cnt,
    const float* __restrict__ fc_w, const float* __restrict__ fc_b, float* __restrict__ out)
{
    int g = blockIdx.x, lane = threadIdx.x;
    float v = pooled[g * CC + lane] / fmaxf(cnt[g], 1.f) * fc_w[lane];
    v = waveReduceSum(v);
    if (lane == 0) out[g] = v + fc_b[0];
}

extern "C" void kernel_launch(void* const* d_in, const int* in_sizes, int n_in,
                              void* d_out, int out_size, void* d_ws, size_t ws_size,
                              hipStream_t stream)
{
    const float* x        = (const float*)d_in[0];
    const float* W1       = (const float*)d_in[1];
    const float* att_src1 = (const float*)d_in[2];
    const float* att_dst1 = (const float*)d_in[3];
    const float* b1       = (const float*)d_in[4];
    const float* W2       = (const float*)d_in[5];
    const float* att_src2 = (const float*)d_in[6];
    const float* att_dst2 = (const float*)d_in[7];
    const float* b2       = (const float*)d_in[8];
    const float* fc_w     = (const float*)d_in[9];
    const float* fc_b     = (const float*)d_in[10];
    const int*   ei       = (const int*)d_in[11];   // [2, E] -> src = ei, dst = ei + EE
    const int*   batch    = (const int*)d_in[12];
    float* out = (float*)d_out;

    char* p = (char*)d_ws;
    __half* W1t   = (__half*)p; p += (size_t)HC * FIN * sizeof(__half);  // 64 KB
    __half* W2t   = (__half*)p; p += (size_t)CC * HC * sizeof(__half);   // 32 KB
    __half* h1    = (__half*)p; p += (size_t)NN * HC * sizeof(__half);   // 25.6 MB
    __half* out1r = (__half*)p; p += (size_t)NN * HC * sizeof(__half);   // 25.6 MB
    __half* h2    = (__half*)p; p += (size_t)NN * CC * sizeof(__half);   // 6.4 MB
    float* a_s1   = (float*)p;  p += (size_t)NN * HH * sizeof(float);
    float* a_d1   = (float*)p;  p += (size_t)NN * HH * sizeof(float);
    float* a_s2   = (float*)p;  p += NN * sizeof(float);
    float* a_d2   = (float*)p;  p += NN * sizeof(float);
    float* pooled = (float*)p;  p += (size_t)GG * CC * sizeof(float);    // pooled+cnt contiguous
    float* cnt    = (float*)p;  p += GG * sizeof(float);
    int* counts   = (int*)p;    p += NN * sizeof(int);
    int* rowptr   = (int*)p;    p += (NN + 1) * sizeof(int);
    int* cursor   = (int*)p;    p += NN * sizeof(int);
    int* scsr     = (int*)p;    p += ET * sizeof(int);
    int* bsum     = (int*)p;    p += SCAN_NB * sizeof(int);

    const int EB = (ET + 255) / 256;

    init0_kernel<<<256, 256, 0, stream>>>(counts, pooled);
    histcnt_kernel<<<EB, 256, 0, stream>>>(ei, counts, batch, cnt);
    cvtw_kernel<<<(HC * FIN + CC * HC) / 256, 256, 0, stream>>>(W1, W2, W1t, W2t);
    scanA_kernel<<<SCAN_NB, 256, 0, stream>>>(counts, bsum);
    scanB_kernel<<<1, 256, 0, stream>>>(bsum);
    scanC_kernel<<<SCAN_NB, 256, 0, stream>>>(counts, bsum, rowptr, cursor);
    fill_kernel<<<EB, 256, 0, stream>>>(ei, cursor, scsr);
    gemm1_mfma_kernel<<<(NN + 31) / 32, 256, 0, stream>>>(x, W1t, att_src1, att_dst1,
                                                          h1, a_s1, a_d1);
    emsg1_kernel<<<NN / 4, 256, 0, stream>>>(rowptr, scsr, a_s1, a_d1,
                                             (const half4*)h1, b1, (half4*)out1r);
    gemm2_mfma_kernel<<<(NN + 63) / 64, 256, 0, stream>>>(out1r, W2t, att_src2, att_dst2,
                                                          h2, a_s2, a_d2);
    emsg2_kernel<<<NN / 4, 256, 0, stream>>>(rowptr, scsr, a_s2, a_d2,
                                             (const half4*)h2, b2, batch, pooled);
    final_kernel<<<GG, 64, 0, stream>>>(pooled, cnt, fc_w, fc_b, out);
}